// Round 6
// baseline (547.939 us; speedup 1.0000x reference)
//
#include <hip/hip_runtime.h>
#include <hip/hip_bf16.h>

#define TT 16000
#define BB 4
#define NLAYER 16
#define NBLK 1000   // kchain grid = 250 x 4; must ALL be co-resident (4 blk/CU x 256 CU = 1024)
#define BARSTR 544  // u32 per layer-barrier: 17 cachelines x 32 u32 (16 shards + root)
#define BARSZ (15 * BARSTR)
#define XCSTR 72    // kchain x-current tile row stride (shorts): 64 + 8
#define XPSTR 72    // kchain x-prev (dilated) tile row stride
#define ACSTR 72    // kchain acts row stride
#define CDSTR 88    // kchain cond row stride (80 + 8 pad; ks6 tail reads pad/next row, finite & A=0)
#define M3STR 264   // kout mid row stride (shorts): 256 + 8 pad

#define A1SZ (NLAYER*8*7*512)   // gate-weight A-frags
#define A2SZ (NLAYER*4*2*512)   // res-weight A-frags
#define SWSZ (16*32*512)        // skip-weight A-frags (M=256, K=1024)
#define OWSZ (16*8*512)         // out/end-weight A-frags (M=256, K=256)
#define AUPSZ (20*10*512)       // upsample A-frags (M=320, K=320)
#define BUPSZ (1000*10*512)     // upsample B-frags (K=320, N=16000)

typedef unsigned short ushort_t;
typedef unsigned long long u64_t;
typedef short v8s __attribute__((ext_vector_type(8)));
typedef short v4s __attribute__((ext_vector_type(4)));
typedef float v4f __attribute__((ext_vector_type(4)));

#define MFMA16 __builtin_amdgcn_mfma_f32_16x16x32_bf16

__device__ __forceinline__ float bf2f(ushort_t u) {
  unsigned int x = ((unsigned int)u) << 16;
  float f; __builtin_memcpy(&f, &x, 4); return f;
}
__device__ __forceinline__ ushort_t f2bf(float f) {
  unsigned int x; __builtin_memcpy(&x, &f, 4);
  x += 0x7fffu + ((x >> 16) & 1u);   // RNE
  return (ushort_t)(x >> 16);
}

// ---------------------------------------------------------------------------
// Prep: pack every weight matrix into exact MFMA fragment order (bf16).
// A-frag: elem j of lane l = A[m = mt*16 + (l&15)][k = ks*32 + (l>>4)*8 + j]
// B-frag: elem j of lane l = B[k = ks*32 + (l>>4)*8 + j][n = nt*16 + (l&15)]
// Also: embed gather -> x0, upsample operands Aup/Bup, barrier zeroing.
// ---------------------------------------------------------------------------
__global__ __launch_bounds__(256) void kprep(
    const float* __restrict__ feat, const int* __restrict__ fin,
    const float* __restrict__ embed, const float* __restrict__ up_w,
    const float* __restrict__ cond_w, const float* __restrict__ cond_b,
    const float* __restrict__ dil_w, const float* __restrict__ dil_b,
    const float* __restrict__ res_w, const float* __restrict__ skip_w,
    const float* __restrict__ skip_b, const float* __restrict__ out_w,
    const float* __restrict__ end_w,
    ushort_t* __restrict__ A1, ushort_t* __restrict__ A2,
    ushort_t* __restrict__ SWf, ushort_t* __restrict__ OWf,
    ushort_t* __restrict__ EWf, ushort_t* __restrict__ Aup,
    ushort_t* __restrict__ Bup, ushort_t* __restrict__ x0,
    float* __restrict__ Bcomb, float* __restrict__ SBsum,
    unsigned int* __restrict__ bar) {
  int tid = blockIdx.x * 256 + threadIdx.x;
  int np = gridDim.x * 256;
  // zero the kchain grid-barrier counters (re-zeroed every iteration/replay)
  for (int idx = tid; idx < BARSZ; idx += np) bar[idx] = 0u;
  // A1: gate GEMM [16 layers][8 Mtiles][7 Ksteps][64 lanes][8]
  // K rows: 0..63 = xc (tap1), 64..127 = xp (tap0), 128..207 = cond, pad=0
  for (int idx = tid; idx < A1SZ; idx += np) {
    int j = idx & 7, lane = (idx >> 3) & 63;
    int r_ = idx >> 9;
    int ks = r_ % 7; int r2 = r_ / 7;
    int mt = r2 & 7; int i = r2 >> 3;
    int m = mt * 16 + (lane & 15);
    int k = ks * 32 + (lane >> 4) * 8 + j;
    float v = 0.f;
    if (k < 64)       v = dil_w[((i * 128 + m) * 64 + k) * 2 + 1];
    else if (k < 128) v = dil_w[((i * 128 + m) * 64 + (k - 64)) * 2 + 0];
    else if (k < 208) v = cond_w[(i * 128 + m) * 80 + (k - 128)];
    A1[idx] = f2bf(v);
  }
  // A2: res GEMM [16][4 Mtiles][2 Ksteps][64][8] (layer 15 zeroed -> the res
  // MFMA at the last layer is a harmless no-op; its result is unused)
  for (int idx = tid; idx < A2SZ; idx += np) {
    int j = idx & 7, lane = (idx >> 3) & 63;
    int r_ = idx >> 9;
    int ks = r_ & 1; int mt = (r_ >> 1) & 3; int i = r_ >> 3;
    int m = mt * 16 + (lane & 15);
    int k = ks * 32 + (lane >> 4) * 8 + j;
    A2[idx] = f2bf(i < 15 ? res_w[(i * 64 + m) * 64 + k] : 0.f);
  }
  // SWf: skip GEMM [16 Mtiles][32 Ksteps][64][8], K = layer*64 + ch
  for (int idx = tid; idx < SWSZ; idx += np) {
    int j = idx & 7, lane = (idx >> 3) & 63;
    int r_ = idx >> 9;
    int ks = r_ & 31; int mt = r_ >> 5;
    int m = mt * 16 + (lane & 15);
    int k = ks * 32 + (lane >> 4) * 8 + j;
    int i = k >> 6, ch = k & 63;
    SWf[idx] = f2bf(skip_w[(i * 256 + m) * 64 + ch]);
  }
  // OWf/EWf: [16 Mtiles][8 Ksteps][64][8]
  for (int idx = tid; idx < OWSZ; idx += np) {
    int j = idx & 7, lane = (idx >> 3) & 63;
    int r_ = idx >> 9;
    int ks = r_ & 7; int mt = r_ >> 3;
    int m = mt * 16 + (lane & 15);
    int k = ks * 32 + (lane >> 4) * 8 + j;
    OWf[idx] = f2bf(out_w[m * 256 + k]);
    EWf[idx] = f2bf(end_w[m * 256 + k]);
  }
  // Aup: [20 Mtiles][10 Ks][64][8]; A[mrow=(b*80+q)][km=(m*80+i)] =
  //   feat[b,i,q-m] (0 if q<m)
  for (int idx = tid; idx < AUPSZ; idx += np) {
    int j = idx & 7, lane = (idx >> 3) & 63;
    int r_ = idx >> 9;
    int ks = r_ % 10; int mt = r_ / 10;
    int mrow = mt * 16 + (lane & 15);
    int km = ks * 32 + (lane >> 4) * 8 + j;
    int b = mrow / 80, q = mrow % 80;
    int m = km / 80, i = km % 80;
    int jj = q - m;
    Aup[idx] = f2bf(jj >= 0 ? feat[(b * 80 + i) * 80 + jj] : 0.f);
  }
  // Bup: [1000 Ntiles][10 Ks][64][8]; B[km][col=(o*200+r)] =
  //   up_w[i, o, 200m + r]
  for (int idx = tid; idx < BUPSZ; idx += np) {
    int j = idx & 7, lane = (idx >> 3) & 63;
    int r_ = idx >> 9;
    int ks = r_ % 10; int nt = r_ / 10;
    int km = ks * 32 + (lane >> 4) * 8 + j;
    int m = km / 80, i = km % 80;
    int col = nt * 16 + (lane & 15);
    int o = col / 200, r = col % 200;
    Bup[idx] = f2bf(up_w[(size_t)(i * 80 + o) * 800 + m * 200 + r]);
  }
  // embed gather: x0[b][t][ch] bf16
  for (int idx = tid; idx < BB * TT * 64; idx += np) {
    int k = idx & 63;
    int bt = idx >> 6;            // b*TT + t
    x0[idx] = f2bf(embed[fin[bt] * 64 + k]);
  }
  for (int idx = tid; idx < NLAYER * 128; idx += np)
    Bcomb[idx] = dil_b[idx] + cond_b[idx];
  for (int idx = tid; idx < 256; idx += np) {
    float s = 0.f;
    for (int i = 0; i < NLAYER; i++) s += skip_b[i * 256 + idx];
    SBsum[idx] = s;
  }
}

// ---------------------------------------------------------------------------
// Upsample GEMM, MFMA: M=320 (b,q), K=320 (m,i), N=16000 (o*200+r).
// Pure register GEMM (no LDS): block = 4 N-tiles (64 cols), wave w owns
// M-tiles w*5..w*5+4. Output cond[b][t][80] bf16, t = q*200+r.
// ---------------------------------------------------------------------------
__global__ __launch_bounds__(256) void kup(
    const ushort_t* __restrict__ Aup, const ushort_t* __restrict__ Bup,
    const float* __restrict__ up_b, ushort_t* __restrict__ cond) {
  int nt0 = blockIdx.x * 4;
  int lane = threadIdx.x & 63;
  int w = threadIdx.x >> 6;
  int tl = lane & 15, quad = lane >> 4;
  v4f acc[5][4];
  #pragma unroll
  for (int mt = 0; mt < 5; mt++)
    #pragma unroll
    for (int nt = 0; nt < 4; nt++) acc[mt][nt] = 0.f;
  #pragma unroll
  for (int ks = 0; ks < 10; ks++) {
    v8s bf[4];
    #pragma unroll
    for (int nt = 0; nt < 4; nt++)
      bf[nt] = *(const v8s*)(Bup + (((size_t)(nt0 + nt) * 10 + ks) * 64 + lane) * 8);
    #pragma unroll
    for (int mt = 0; mt < 5; mt++) {
      v8s a = *(const v8s*)(Aup + (((size_t)(w * 5 + mt) * 10 + ks) * 64 + lane) * 8);
      #pragma unroll
      for (int nt = 0; nt < 4; nt++)
        acc[mt][nt] = MFMA16(a, bf[nt], acc[mt][nt], 0, 0, 0);
    }
  }
  #pragma unroll
  for (int mt = 0; mt < 5; mt++) {
    #pragma unroll
    for (int nt = 0; nt < 4; nt++) {
      int col = (nt0 + nt) * 16 + tl;
      int o = col / 200, r = col % 200;
      float bias = up_b[o];
      #pragma unroll
      for (int rg = 0; rg < 4; rg++) {
        int mrow = (w * 5 + mt) * 16 + quad * 4 + rg;
        int b = mrow / 80, q = mrow % 80;
        cond[((size_t)b * TT + q * 200 + r) * 80 + o] = f2bf(acc[mt][nt][rg] + bias);
      }
    }
  }
}

// ---------------------------------------------------------------------------
// Fused 16-layer WaveNet chain + SKIP GEMM — ONE kernel. Sync machinery is
// r4's PROVEN sharded global barrier + ping-pong halo stores, byte-identical
// (r5's p2p-flag variant crashed; this round isolates the skip fusion).
//
// Skip fusion: the skip GEMM's B-frags are EXACTLY the res GEMM's B-frags
// (same Uact reads, same lane layout). accS[4][4] (64 VGPR, init SBsum)
// accumulates sum_l SW_l * acts_l across all 16 layers; epilogue writes
// relu'd bf16 M3. The acts buffer (131 MB store + 131 MB load) is DELETED.
// Stage 2 runs at l=15 too (A2 zeroed there -> res MFMA no-op, unused).
//
// Co-residency (barrier deadlock safety): LDS 38.9 KB -> 4 blk/CU;
// launch_bounds(256,4) pins VGPR<=128 -> capacity 1024 >= 1000.
// ---------------------------------------------------------------------------
__global__ __launch_bounds__(256, 4) void kchain(
    ushort_t* __restrict__ x0g, ushort_t* __restrict__ x1g,
    const ushort_t* __restrict__ cond,
    const ushort_t* __restrict__ A1, const ushort_t* __restrict__ A2,
    const ushort_t* __restrict__ SWf,
    const float* __restrict__ Bcomb, const float* __restrict__ resb,
    const float* __restrict__ SBsum,
    ushort_t* __restrict__ M3g, unsigned int* __restrict__ bar) {
  __shared__ ushort_t Uxc[64 * XCSTR];       // 9.0 KB current x tile
  __shared__ ushort_t Uxp[64 * XPSTR];       // 9.0 KB dilated-prev tile
  __shared__ ushort_t Uact[64 * ACSTR];      // 9.0 KB gate acts
  __shared__ ushort_t Ucd[64 * CDSTR + 8];   // 11.0 KB cond tile (+tail pad)
  int b = blockIdx.y;
  int t0 = blockIdx.x * 64;
  int tidx = threadIdx.x;
  int lane = tidx & 63;
  int w = tidx >> 6;
  int tl = lane & 15, quad = lane >> 4;
  int cha = w * 16 + quad * 4;

  // ---- one-time stage: Uxc <- x0, Ucd <- cond, zero cond pad ----
  const ushort_t* xb0 = x0g + ((size_t)b * TT + t0) * 64;
  for (int e = tidx * 8; e < 4096; e += 2048) {
    int t = e >> 6, c = e & 63;
    *(v8s*)&Uxc[t * XCSTR + c] = *(const v8s*)(xb0 + e);
  }
  const ushort_t* cbp = cond + ((size_t)b * TT + t0) * 80;
  for (int e = tidx * 8; e < 5120; e += 2048) {
    int t = e / 80, c = e - t * 80;
    *(v8s*)&Ucd[t * CDSTR + c] = *(const v8s*)(cbp + e);
  }
  // zero pad cols 80..87 every row + 8 tail shorts (ks6 reads must be finite)
  for (int e2 = tidx; e2 < 520; e2 += 256) {
    if (e2 < 512) Ucd[(e2 >> 3) * CDSTR + 80 + (e2 & 7)] = 0;
    else          Ucd[64 * CDSTR + (e2 - 512)] = 0;
  }

  // ---- persistent skip accumulator (64 VGPR, init SBsum) ----
  v4f accS[4][4];
  #pragma unroll
  for (int mt = 0; mt < 4; mt++) {
    int o = (w * 4 + mt) * 16 + quad * 4;
    v4f z;
    #pragma unroll
    for (int r = 0; r < 4; r++) z[r] = SBsum[o + r];
    #pragma unroll
    for (int nt = 0; nt < 4; nt++) accS[mt][nt] = z;
  }
  __syncthreads();

  for (int l = 0; l < NLAYER; l++) {
    int d = 1 << (l & 7);
    const ushort_t* xing = (l & 1) ? x1g : x0g;
    ushort_t* xoutg = (l & 1) ? x0g : x1g;
    const ushort_t* A1l = A1 + (size_t)l * 8 * 7 * 512;
    const ushort_t* A2l = A2 + (size_t)l * 4 * 2 * 512;
    const float* Bb = Bcomb + l * 128;
    const float* rb = resb + (l < 15 ? l : 0) * 64;
    int last = (l == NLAYER - 1);

    // ---- stage Uxp: rows t>=d shift from resident Uxc; rows t<d come
    //      from the left neighbors' halo (LLC-coherent atomic loads) ----
    for (int e = tidx * 8; e < 4096; e += 2048) {
      int t = e >> 6, c = e & 63;
      v8s v;
      if (t >= d) {
        v = *(const v8s*)&Uxc[(t - d) * XCSTR + c];
      } else {
        int tp = t0 + t - d;
        v = (v8s)0;
        if (tp >= 0) {
          const u64_t* p = (const u64_t*)(xing + ((size_t)b * TT + tp) * 64 + c);
          u64_t w0 = __hip_atomic_load(p, __ATOMIC_RELAXED, __HIP_MEMORY_SCOPE_AGENT);
          u64_t w1 = __hip_atomic_load(p + 1, __ATOMIC_RELAXED, __HIP_MEMORY_SCOPE_AGENT);
          __builtin_memcpy(&v, &w0, 8);
          __builtin_memcpy(((char*)&v) + 8, &w1, 8);
        }
      }
      *(v8s*)&Uxp[t * XPSTR + c] = v;
    }
    __syncthreads();

    // ---- stage 1: gate GEMM (region-split B reads) ----
    v4f acc0[4], acc1[4];
    #pragma unroll
    for (int nt = 0; nt < 4; nt++) { acc0[nt] = 0.f; acc1[nt] = 0.f; }
    #pragma unroll
    for (int ks = 0; ks < 7; ks++) {
      v8s a0 = *(const v8s*)(A1l + (((size_t)w * 7 + ks) * 64 + lane) * 8);
      v8s a1 = *(const v8s*)(A1l + (((size_t)(w + 4) * 7 + ks) * 64 + lane) * 8);
      #pragma unroll
      for (int nt = 0; nt < 4; nt++) {
        int t = nt * 16 + tl;
        const ushort_t* bp;
        if (ks < 2)      bp = &Uxc[t * XCSTR + ks * 32 + quad * 8];
        else if (ks < 4) bp = &Uxp[t * XPSTR + (ks - 2) * 32 + quad * 8];
        else             bp = &Ucd[t * CDSTR + (ks - 4) * 32 + quad * 8];
        v8s bf = *(const v8s*)bp;
        acc0[nt] = MFMA16(a0, bf, acc0[nt], 0, 0, 0);
        acc1[nt] = MFMA16(a1, bf, acc1[nt], 0, 0, 0);
      }
    }

    // ---- gates: ch = w*16 + quad*4 + r (pair ch, ch+64 lane-local) ----
    float ba[4], bb_[4];
    #pragma unroll
    for (int r = 0; r < 4; r++) { ba[r] = Bb[cha + r]; bb_[r] = Bb[64 + cha + r]; }
    #pragma unroll
    for (int nt = 0; nt < 4; nt++) {
      int t = nt * 16 + tl;
      v4s pk;
      #pragma unroll
      for (int r = 0; r < 4; r++) {
        float ia = acc0[nt][r] + ba[r];
        float ib = acc1[nt][r] + bb_[r];
        float ax = fabsf(ia);
        float e2 = __expf(-2.f * ax);
        float th = __builtin_copysignf((1.f - e2) / (1.f + e2), ia);
        float sg = 1.f / (1.f + __expf(-ib));
        pk[r] = (short)f2bf(th * sg);
      }
      *(v4s*)&Uact[t * ACSTR + cha] = pk;
    }
    __syncthreads();

    // ---- stage 2: res GEMM + SKIP GEMM (shared B-frags; runs at l=15
    //      too — A2 is zeroed there, acc2 unused) ----
    v4f acc2[4];
    #pragma unroll
    for (int nt = 0; nt < 4; nt++) {
      v4f z;
      #pragma unroll
      for (int r = 0; r < 4; r++) z[r] = rb[cha + r];
      acc2[nt] = z;
    }
    #pragma unroll
    for (int ks = 0; ks < 2; ks++) {
      v8s a2 = *(const v8s*)(A2l + (((size_t)w * 2 + ks) * 64 + lane) * 8);
      v8s sw[4];
      #pragma unroll
      for (int mt = 0; mt < 4; mt++)
        sw[mt] = *(const v8s*)(SWf +
            (((size_t)(w * 4 + mt) * 32 + (size_t)l * 2 + ks) * 64 + lane) * 8);
      #pragma unroll
      for (int nt = 0; nt < 4; nt++) {
        v8s bf = *(const v8s*)&Uact[(nt * 16 + tl) * ACSTR + ks * 32 + quad * 8];
        acc2[nt] = MFMA16(a2, bf, acc2[nt], 0, 0, 0);
        #pragma unroll
        for (int mt = 0; mt < 4; mt++)
          accS[mt][nt] = MFMA16(sw[mt], bf, accS[mt][nt], 0, 0, 0);
      }
    }

    if (!last) {
      // ---- residual: Uxc updated IN PLACE (vectorized v4s) ----
      #pragma unroll
      for (int nt = 0; nt < 4; nt++) {
        int t = nt * 16 + tl;
        v4s xo = *(const v4s*)&Uxc[t * XCSTR + cha];
        v4s nw;
        #pragma unroll
        for (int r = 0; r < 4; r++)
          nw[r] = (short)f2bf(acc2[nt][r] + bf2f((ushort_t)xo[r]));
        *(v4s*)&Uxc[t * XCSTR + cha] = nw;
      }
      __syncthreads();   // all channels updated before halo snapshot

      // ---- xout halo rows -> LLC via relaxed agent atomics (sc1) ----
      int dnext = 1 << ((l + 1) & 7);
      int tmin = 64 - (dnext < 64 ? dnext : 64);
      ushort_t* xob = xoutg + ((size_t)b * TT + t0) * 64;
      for (int e = tidx * 8; e < 4096; e += 2048) {
        int t = e >> 6, c = e & 63;
        if (t >= tmin) {
          v8s v = *(const v8s*)&Uxc[t * XCSTR + c];
          u64_t w0, w1;
          __builtin_memcpy(&w0, &v, 8);
          __builtin_memcpy(&w1, ((const char*)&v) + 8, 8);
          u64_t* p = (u64_t*)(xob + e);
          __hip_atomic_store(p, w0, __ATOMIC_RELAXED, __HIP_MEMORY_SCOPE_AGENT);
          __hip_atomic_store(p + 1, w1, __ATOMIC_RELAXED, __HIP_MEMORY_SCOPE_AGENT);
        }
      }

      // ---- fence-free sharded grid barrier (r4-proven) ----
      __syncthreads();     // drains vmcnt: all halo stores globally visible
      if (tidx == 0) {
        unsigned int* L = bar + l * BARSTR;
        int flat = b * 250 + blockIdx.x;           // 0..999
        int shard = flat & 15;                     // shards 0..7: 63 blks, 8..15: 62
        unsigned int tgt = (shard < 8) ? 62u : 61u;
        unsigned int old = __hip_atomic_fetch_add(L + shard * 32, 1u,
            __ATOMIC_RELAXED, __HIP_MEMORY_SCOPE_AGENT);
        if (old == tgt)
          __hip_atomic_fetch_add(L + 16 * 32, 1u,
              __ATOMIC_RELAXED, __HIP_MEMORY_SCOPE_AGENT);
        while (__hip_atomic_load(L + 16 * 32,
            __ATOMIC_RELAXED, __HIP_MEMORY_SCOPE_AGENT) < 16u)
          __builtin_amdgcn_s_sleep(2);
      }
      __syncthreads();
    }
  }

  // ---- epilogue: relu(skip sum) -> bf16 M3 [b][t][256] ----
  #pragma unroll
  for (int mt = 0; mt < 4; mt++) {
    int o = (w * 4 + mt) * 16 + quad * 4;
    #pragma unroll
    for (int nt = 0; nt < 4; nt++) {
      int t = nt * 16 + tl;
      v4s pk;
      #pragma unroll
      for (int r = 0; r < 4; r++)
        pk[r] = (short)f2bf(fmaxf(accS[mt][nt][r], 0.f));
      *(v4s*)(M3g + (((size_t)b * TT + t0 + t) << 8) + o) = pk;
    }
  }
}

// ---------------------------------------------------------------------------
// Output head: M3 (bf16 [b][t][256]) -> out GEMM (K=256) -> relu ->
// end GEMM (K=256) -> shifted f32 store. LDS 33.8 KB.
// ---------------------------------------------------------------------------
__global__ __launch_bounds__(256) void kout(
    const ushort_t* __restrict__ M3g,
    const ushort_t* __restrict__ OWf, const ushort_t* __restrict__ EWf,
    float* __restrict__ dout) {
  __shared__ ushort_t SMEM[64 * M3STR];
  int b = blockIdx.y;
  int t0 = blockIdx.x * 64;
  int tidx = threadIdx.x;
  int lane = tidx & 63;
  int w = tidx >> 6;
  int tl = lane & 15, quad = lane >> 4;

  // ---- stage M3 tile [64 t][256] ----
  const ushort_t* mb = M3g + (((size_t)b * TT + t0) << 8);
  for (int e = tidx * 8; e < 16384; e += 2048) {
    int t = e >> 8, c = e & 255;
    *(v8s*)&SMEM[t * M3STR + c] = *(const v8s*)(mb + e);
  }
  __syncthreads();

  // ---- out GEMM, K=256 ----
  v4f acc2[4][4];
  #pragma unroll
  for (int mt = 0; mt < 4; mt++)
    #pragma unroll
    for (int nt = 0; nt < 4; nt++) acc2[mt][nt] = 0.f;
  #pragma unroll
  for (int ks = 0; ks < 8; ks++) {
    v8s bf[4];
    #pragma unroll
    for (int nt = 0; nt < 4; nt++)
      bf[nt] = *(const v8s*)&SMEM[(nt * 16 + tl) * M3STR + ks * 32 + quad * 8];
    #pragma unroll
    for (int mt = 0; mt < 4; mt++) {
      v8s a = *(const v8s*)(OWf + (((size_t)(w * 4 + mt) * 8 + ks) * 64 + lane) * 8);
      #pragma unroll
      for (int nt = 0; nt < 4; nt++)
        acc2[mt][nt] = MFMA16(a, bf[nt], acc2[mt][nt], 0, 0, 0);
    }
  }
  __syncthreads();   // all reads done before overwrite
  #pragma unroll
  for (int mt = 0; mt < 4; mt++) {
    int o = (w * 4 + mt) * 16 + quad * 4;
    #pragma unroll
    for (int nt = 0; nt < 4; nt++) {
      int t = nt * 16 + tl;
      #pragma unroll
      for (int r = 0; r < 4; r++)
        SMEM[t * M3STR + o + r] = f2bf(fmaxf(acc2[mt][nt][r], 0.f));
    }
  }
  __syncthreads();

  // ---- end GEMM, K=256, then shifted store ----
  v4f acc3[4][4];
  #pragma unroll
  for (int mt = 0; mt < 4; mt++)
    #pragma unroll
    for (int nt = 0; nt < 4; nt++) acc3[mt][nt] = 0.f;
  #pragma unroll
  for (int ks = 0; ks < 8; ks++) {
    v8s bf[4];
    #pragma unroll
    for (int nt = 0; nt < 4; nt++)
      bf[nt] = *(const v8s*)&SMEM[(nt * 16 + tl) * M3STR + ks * 32 + quad * 8];
    #pragma unroll
    for (int mt = 0; mt < 4; mt++) {
      v8s a = *(const v8s*)(EWf + (((size_t)(w * 4 + mt) * 8 + ks) * 64 + lane) * 8);
      #pragma unroll
      for (int nt = 0; nt < 4; nt++)
        acc3[mt][nt] = MFMA16(a, bf[nt], acc3[mt][nt], 0, 0, 0);
    }
  }
  #pragma unroll
  for (int mt = 0; mt < 4; mt++) {
    #pragma unroll
    for (int nt = 0; nt < 4; nt++) {
      int tg = t0 + nt * 16 + tl;
      #pragma unroll
      for (int r = 0; r < 4; r++) {
        int o = (w * 4 + mt) * 16 + quad * 4 + r;
        float* ob = dout + ((size_t)b * 256 + o) * TT;
        if (tg == 0) ob[0] = 0.f;
        if (tg + 1 < TT) ob[tg + 1] = acc3[mt][nt][r];
      }
    }
  }
}

// ---------------------------------------------------------------------------
extern "C" void kernel_launch(void* const* d_in, const int* in_sizes, int n_in,
                              void* d_out, int out_size, void* d_ws, size_t ws_size,
                              hipStream_t stream) {
  const float* feat   = (const float*)d_in[0];
  const int*   fin    = (const int*)d_in[1];
  const float* embed  = (const float*)d_in[2];
  const float* up_w   = (const float*)d_in[3];
  const float* up_b   = (const float*)d_in[4];
  const float* cond_w = (const float*)d_in[5];
  const float* cond_b = (const float*)d_in[6];
  const float* dil_w  = (const float*)d_in[7];
  const float* dil_b  = (const float*)d_in[8];
  const float* res_w  = (const float*)d_in[9];
  const float* res_b  = (const float*)d_in[10];
  const float* skip_w = (const float*)d_in[11];
  const float* skip_b = (const float*)d_in[12];
  const float* out_w  = (const float*)d_in[13];
  const float* end_w  = (const float*)d_in[14];

  // Workspace (~75 MB).
  float* ws = (float*)d_ws;
  unsigned int* bar = (unsigned int*)ws;          // sharded barrier counters
  size_t off = BARSZ;
  float* Bcomb = ws + off; off += NLAYER * 128;
  float* SBsum = ws + off; off += 256;
  ushort_t* ub = (ushort_t*)(ws + off);
  size_t uo = 0;
  ushort_t* A1   = ub + uo; uo += A1SZ;
  ushort_t* A2   = ub + uo; uo += A2SZ;
  ushort_t* SWf  = ub + uo; uo += SWSZ;
  ushort_t* OWf  = ub + uo; uo += OWSZ;
  ushort_t* EWf  = ub + uo; uo += OWSZ;
  ushort_t* Aup  = ub + uo; uo += AUPSZ;
  ushort_t* Bup  = ub + uo; uo += BUPSZ;
  ushort_t* cond = ub + uo; uo += (size_t)BB * TT * 80;
  ushort_t* x0   = ub + uo; uo += (size_t)BB * TT * 64;
  ushort_t* x1   = ub + uo; uo += (size_t)BB * TT * 64;
  ushort_t* M3   = ub + uo; uo += (size_t)BB * TT * 256;   // 32.8 MB

  kprep<<<1024, 256, 0, stream>>>(feat, fin, embed, up_w, cond_w, cond_b,
      dil_w, dil_b, res_w, skip_w, skip_b, out_w, end_w,
      A1, A2, SWf, OWf, EWf, Aup, Bup, x0, Bcomb, SBsum, bar);
  kup<<<250, 256, 0, stream>>>(Aup, Bup, up_b, cond);
  kchain<<<dim3(250, BB), 256, 0, stream>>>(x0, x1, cond,
      A1, A2, SWf, Bcomb, res_b, SBsum, M3, bar);
  kout<<<dim3(250, BB), 256, 0, stream>>>(M3, OWf, EWf, (float*)d_out);
}

// Round 7
// 467.139 us; speedup vs baseline: 1.1730x; 1.1730x over previous
//
#include <hip/hip_runtime.h>
#include <hip/hip_bf16.h>

#define TT 16000
#define BB 4
#define NLAYER 16
#define NBLK 1000    // kchain grid = 250 x 4; ALL co-resident (4 blk/CU x 256 CU = 1024)
#define BARSTR 1088  // u32 per layer-barrier: 34 lines (16 shard + root + 16 release + pad)
#define BARSZ (15 * BARSTR)
#define XCSTR 72    // kchain x-current tile row stride (shorts): 64 + 8
#define XPSTR 72    // kchain halo tile row stride
#define ACSTR 72    // kchain acts row stride
#define CDSTR 88    // kchain cond row stride (80 + 8 pad; ks6 tail reads pad/next row, finite & A=0)
#define M3STR 264   // kfinal mid row stride (shorts): 256 + 8 pad
#define ABSTR 72    // kfinal acts-stage row stride (shorts): 64 + 8 pad

#define A1SZ (NLAYER*8*7*512)   // gate-weight A-frags
#define A2SZ (NLAYER*4*2*512)   // res-weight A-frags
#define SWSZ (16*32*512)        // skip-weight A-frags (M=256, K=1024)
#define OWSZ (16*8*512)         // out/end-weight A-frags (M=256, K=256)
#define AUPSZ (20*10*512)       // upsample A-frags (M=320, K=320)
#define BUPSZ (1000*10*512)     // upsample B-frags (K=320, N=16000)

typedef unsigned short ushort_t;
typedef unsigned long long u64_t;
typedef short v8s __attribute__((ext_vector_type(8)));
typedef short v4s __attribute__((ext_vector_type(4)));
typedef float v4f __attribute__((ext_vector_type(4)));

#define MFMA16 __builtin_amdgcn_mfma_f32_16x16x32_bf16

__device__ __forceinline__ float bf2f(ushort_t u) {
  unsigned int x = ((unsigned int)u) << 16;
  float f; __builtin_memcpy(&f, &x, 4); return f;
}
__device__ __forceinline__ ushort_t f2bf(float f) {
  unsigned int x; __builtin_memcpy(&x, &f, 4);
  x += 0x7fffu + ((x >> 16) & 1u);   // RNE
  return (ushort_t)(x >> 16);
}

// ---------------------------------------------------------------------------
// Prep: pack every weight matrix into exact MFMA fragment order (bf16).
// A-frag: elem j of lane l = A[m = mt*16 + (l&15)][k = ks*32 + (l>>4)*8 + j]
// B-frag: elem j of lane l = B[k = ks*32 + (l>>4)*8 + j][n = nt*16 + (l&15)]
// Also: embed gather -> x0, upsample operands Aup/Bup, barrier zeroing.
// Bup fill is READ-LINEAR over up_w (coalesced 4B reads; the old mapping
// read up_w at 3.2KB stride = 5.1M scattered reads thrashing L2).
// ---------------------------------------------------------------------------
__global__ __launch_bounds__(256) void kprep(
    const float* __restrict__ feat, const int* __restrict__ fin,
    const float* __restrict__ embed, const float* __restrict__ up_w,
    const float* __restrict__ cond_w, const float* __restrict__ cond_b,
    const float* __restrict__ dil_w, const float* __restrict__ dil_b,
    const float* __restrict__ res_w, const float* __restrict__ skip_w,
    const float* __restrict__ skip_b, const float* __restrict__ out_w,
    const float* __restrict__ end_w,
    ushort_t* __restrict__ A1, ushort_t* __restrict__ A2,
    ushort_t* __restrict__ SWf, ushort_t* __restrict__ OWf,
    ushort_t* __restrict__ EWf, ushort_t* __restrict__ Aup,
    ushort_t* __restrict__ Bup, ushort_t* __restrict__ x0,
    float* __restrict__ Bcomb, float* __restrict__ SBsum,
    unsigned int* __restrict__ bar) {
  int tid = blockIdx.x * 256 + threadIdx.x;
  int np = gridDim.x * 256;
  // zero the kchain grid-barrier state (re-zeroed every iteration/replay)
  for (int idx = tid; idx < BARSZ; idx += np) bar[idx] = 0u;
  // A1: gate GEMM [16 layers][8 Mtiles][7 Ksteps][64 lanes][8]
  // K rows: 0..63 = xc (tap1), 64..127 = xp (tap0), 128..207 = cond, pad=0
  for (int idx = tid; idx < A1SZ; idx += np) {
    int j = idx & 7, lane = (idx >> 3) & 63;
    int r_ = idx >> 9;
    int ks = r_ % 7; int r2 = r_ / 7;
    int mt = r2 & 7; int i = r2 >> 3;
    int m = mt * 16 + (lane & 15);
    int k = ks * 32 + (lane >> 4) * 8 + j;
    float v = 0.f;
    if (k < 64)       v = dil_w[((i * 128 + m) * 64 + k) * 2 + 1];
    else if (k < 128) v = dil_w[((i * 128 + m) * 64 + (k - 64)) * 2 + 0];
    else if (k < 208) v = cond_w[(i * 128 + m) * 80 + (k - 128)];
    A1[idx] = f2bf(v);
  }
  // A2: res GEMM [16][4 Mtiles][2 Ksteps][64][8] (layer 15 zeroed/unused)
  for (int idx = tid; idx < A2SZ; idx += np) {
    int j = idx & 7, lane = (idx >> 3) & 63;
    int r_ = idx >> 9;
    int ks = r_ & 1; int mt = (r_ >> 1) & 3; int i = r_ >> 3;
    int m = mt * 16 + (lane & 15);
    int k = ks * 32 + (lane >> 4) * 8 + j;
    A2[idx] = f2bf(i < 15 ? res_w[(i * 64 + m) * 64 + k] : 0.f);
  }
  // SWf: skip GEMM [16 Mtiles][32 Ksteps][64][8], K = layer*64 + ch
  for (int idx = tid; idx < SWSZ; idx += np) {
    int j = idx & 7, lane = (idx >> 3) & 63;
    int r_ = idx >> 9;
    int ks = r_ & 31; int mt = r_ >> 5;
    int m = mt * 16 + (lane & 15);
    int k = ks * 32 + (lane >> 4) * 8 + j;
    int i = k >> 6, ch = k & 63;
    SWf[idx] = f2bf(skip_w[(i * 256 + m) * 64 + ch]);
  }
  // OWf/EWf: [16 Mtiles][8 Ksteps][64][8]
  for (int idx = tid; idx < OWSZ; idx += np) {
    int j = idx & 7, lane = (idx >> 3) & 63;
    int r_ = idx >> 9;
    int ks = r_ & 7; int mt = r_ >> 3;
    int m = mt * 16 + (lane & 15);
    int k = ks * 32 + (lane >> 4) * 8 + j;
    OWf[idx] = f2bf(out_w[m * 256 + k]);
    EWf[idx] = f2bf(end_w[m * 256 + k]);
  }
  // Aup: [20 Mtiles][10 Ks][64][8]; A[mrow=(b*80+q)][km=(m*80+i)] =
  //   feat[b,i,q-m] (0 if q<m)
  for (int idx = tid; idx < AUPSZ; idx += np) {
    int j = idx & 7, lane = (idx >> 3) & 63;
    int r_ = idx >> 9;
    int ks = r_ % 10; int mt = r_ / 10;
    int mrow = mt * 16 + (lane & 15);
    int km = ks * 32 + (lane >> 4) * 8 + j;
    int b = mrow / 80, q = mrow % 80;
    int m = km / 80, i = km % 80;
    int jj = q - m;
    Aup[idx] = f2bf(jj >= 0 ? feat[(b * 80 + i) * 80 + jj] : 0.f);
  }
  // Bup: read-linear over up_w[i(80)][o(80)][kk=800]; dest frag index
  // derived: km=m*80+i -> (ks,lanehi,j); col=o*200+r -> (nt,tl)
  for (size_t idx = tid; idx < (size_t)80 * 80 * 800; idx += np) {
    int kk = (int)(idx % 800); int io = (int)(idx / 800);
    int o = io % 80, i = io / 80;
    int m = kk / 200, r = kk - m * 200;
    int col = o * 200 + r;
    int nt = col >> 4, tl = col & 15;
    int km = m * 80 + i;
    int ks = km >> 5, j = km & 7;
    int lane = (((km >> 3) & 3) << 4) | tl;
    Bup[(((size_t)nt * 10 + ks) * 64 + lane) * 8 + j] = f2bf(up_w[idx]);
  }
  // embed gather: x0[b][t][ch] bf16
  for (int idx = tid; idx < BB * TT * 64; idx += np) {
    int k = idx & 63;
    int bt = idx >> 6;            // b*TT + t
    x0[idx] = f2bf(embed[fin[bt] * 64 + k]);
  }
  for (int idx = tid; idx < NLAYER * 128; idx += np)
    Bcomb[idx] = dil_b[idx] + cond_b[idx];
  for (int idx = tid; idx < 256; idx += np) {
    float s = 0.f;
    for (int i = 0; i < NLAYER; i++) s += skip_b[i * 256 + idx];
    SBsum[idx] = s;
  }
}

// ---------------------------------------------------------------------------
// Upsample GEMM, MFMA: M=320 (b,q), K=320 (m,i), N=16000 (o*200+r).
// ---------------------------------------------------------------------------
__global__ __launch_bounds__(256) void kup(
    const ushort_t* __restrict__ Aup, const ushort_t* __restrict__ Bup,
    const float* __restrict__ up_b, ushort_t* __restrict__ cond) {
  int nt0 = blockIdx.x * 4;
  int lane = threadIdx.x & 63;
  int w = threadIdx.x >> 6;
  int tl = lane & 15, quad = lane >> 4;
  v4f acc[5][4];
  #pragma unroll
  for (int mt = 0; mt < 5; mt++)
    #pragma unroll
    for (int nt = 0; nt < 4; nt++) acc[mt][nt] = 0.f;
  #pragma unroll
  for (int ks = 0; ks < 10; ks++) {
    v8s bf[4];
    #pragma unroll
    for (int nt = 0; nt < 4; nt++)
      bf[nt] = *(const v8s*)(Bup + (((size_t)(nt0 + nt) * 10 + ks) * 64 + lane) * 8);
    #pragma unroll
    for (int mt = 0; mt < 5; mt++) {
      v8s a = *(const v8s*)(Aup + (((size_t)(w * 5 + mt) * 10 + ks) * 64 + lane) * 8);
      #pragma unroll
      for (int nt = 0; nt < 4; nt++)
        acc[mt][nt] = MFMA16(a, bf[nt], acc[mt][nt], 0, 0, 0);
    }
  }
  #pragma unroll
  for (int mt = 0; mt < 5; mt++) {
    #pragma unroll
    for (int nt = 0; nt < 4; nt++) {
      int col = (nt0 + nt) * 16 + tl;
      int o = col / 200, r = col % 200;
      float bias = up_b[o];
      #pragma unroll
      for (int rg = 0; rg < 4; rg++) {
        int mrow = (w * 5 + mt) * 16 + quad * 4 + rg;
        int b = mrow / 80, q = mrow % 80;
        cond[((size_t)b * TT + q * 200 + r) * 80 + o] = f2bf(acc[mt][nt][rg] + bias);
      }
    }
  }
}

// ---------------------------------------------------------------------------
// Fused 16-layer WaveNet chain — r4 data flow (acts written for kfinal),
// with two fixes:
//  (1) NO Uxp bulk copy: gate GEMM xp-frags select per-lane between the
//      resident Uxc[t-d] (t>=d) and a small Uhalo[t] staged with only the
//      min(d,64) halo rows from global.
//  (2) Hierarchical barrier release: 16 shard counters -> root (leaders
//      only) -> last leader broadcasts 16 per-shard RELEASE lines; each
//      block polls ONLY its shard's line with s_sleep(16). Kills the
//      1000-blocks-on-one-line poll convoy measured in r4/r6 FETCH.
// All cross-block data via RELAXED agent atomics (LLC-coherent, no
// cache-maintenance ops — r3 lesson).
// ---------------------------------------------------------------------------
__global__ __launch_bounds__(256, 4) void kchain(
    ushort_t* __restrict__ x0g, ushort_t* __restrict__ x1g,
    const ushort_t* __restrict__ cond, ushort_t* __restrict__ actsb,
    const ushort_t* __restrict__ A1, const ushort_t* __restrict__ A2,
    const float* __restrict__ Bcomb, const float* __restrict__ resb,
    unsigned int* __restrict__ bar) {
  __shared__ ushort_t Uxc[64 * XCSTR];       // 9.0 KB current x tile
  __shared__ ushort_t Uhalo[64 * XPSTR];     // 9.0 KB halo rows (t < d)
  __shared__ ushort_t Uact[64 * ACSTR];      // 9.0 KB gate acts
  __shared__ ushort_t Ucd[64 * CDSTR + 8];   // 11.0 KB cond tile (+tail pad)
  int b = blockIdx.y;
  int t0 = blockIdx.x * 64;
  int tidx = threadIdx.x;
  int lane = tidx & 63;
  int w = tidx >> 6;
  int tl = lane & 15, quad = lane >> 4;
  int cha = w * 16 + quad * 4;
  const size_t lstr = (size_t)BB * TT * 64;

  // ---- one-time stage: Uxc <- x0, Ucd <- cond, zero cond pad ----
  const ushort_t* xb0 = x0g + ((size_t)b * TT + t0) * 64;
  for (int e = tidx * 8; e < 4096; e += 2048) {
    int t = e >> 6, c = e & 63;
    *(v8s*)&Uxc[t * XCSTR + c] = *(const v8s*)(xb0 + e);
  }
  const ushort_t* cbp = cond + ((size_t)b * TT + t0) * 80;
  for (int e = tidx * 8; e < 5120; e += 2048) {
    int t = e / 80, c = e - t * 80;
    *(v8s*)&Ucd[t * CDSTR + c] = *(const v8s*)(cbp + e);
  }
  // zero pad cols 80..87 every row + 8 tail shorts (ks6 reads must be finite)
  for (int e2 = tidx; e2 < 520; e2 += 256) {
    if (e2 < 512) Ucd[(e2 >> 3) * CDSTR + 80 + (e2 & 7)] = 0;
    else          Ucd[64 * CDSTR + (e2 - 512)] = 0;
  }
  __syncthreads();

  for (int l = 0; l < NLAYER; l++) {
    int d = 1 << (l & 7);
    int hr = (d < 64) ? d : 64;                 // halo rows staged this layer
    const ushort_t* xing = (l & 1) ? x1g : x0g;
    ushort_t* xoutg = (l & 1) ? x0g : x1g;
    const ushort_t* A1l = A1 + (size_t)l * 8 * 7 * 512;
    const ushort_t* A2l = A2 + (size_t)l * 4 * 2 * 512;
    const float* Bb = Bcomb + l * 128;
    const float* rb = resb + (l < 15 ? l : 0) * 64;
    int last = (l == NLAYER - 1);

    // ---- stage Uhalo: ONLY rows t<hr, from left neighbor (LLC atomics) ----
    for (int e = tidx * 8; e < hr * 64; e += 2048) {
      int t = e >> 6, c = e & 63;
      int tp = t0 + t - d;
      v8s v = (v8s)0;
      if (tp >= 0) {
        const u64_t* p = (const u64_t*)(xing + ((size_t)b * TT + tp) * 64 + c);
        u64_t w0 = __hip_atomic_load(p, __ATOMIC_RELAXED, __HIP_MEMORY_SCOPE_AGENT);
        u64_t w1 = __hip_atomic_load(p + 1, __ATOMIC_RELAXED, __HIP_MEMORY_SCOPE_AGENT);
        __builtin_memcpy(&v, &w0, 8);
        __builtin_memcpy(((char*)&v) + 8, &w1, 8);
      }
      *(v8s*)&Uhalo[t * XPSTR + c] = v;
    }
    __syncthreads();

    // ---- stage 1: gate GEMM (xc from Uxc rows t; xp from Uxc[t-d] or
    //      Uhalo[t]; cond from Ucd) ----
    v4f acc0[4], acc1[4];
    #pragma unroll
    for (int nt = 0; nt < 4; nt++) { acc0[nt] = 0.f; acc1[nt] = 0.f; }
    #pragma unroll
    for (int ks = 0; ks < 7; ks++) {
      v8s a0 = *(const v8s*)(A1l + (((size_t)w * 7 + ks) * 64 + lane) * 8);
      v8s a1 = *(const v8s*)(A1l + (((size_t)(w + 4) * 7 + ks) * 64 + lane) * 8);
      #pragma unroll
      for (int nt = 0; nt < 4; nt++) {
        int t = nt * 16 + tl;
        const ushort_t* bp;
        if (ks < 2) {
          bp = &Uxc[t * XCSTR + ks * 32 + quad * 8];
        } else if (ks < 4) {
          int toff = t - d;
          bp = (toff >= 0) ? &Uxc[toff * XCSTR + (ks - 2) * 32 + quad * 8]
                           : &Uhalo[t * XPSTR + (ks - 2) * 32 + quad * 8];
        } else {
          bp = &Ucd[t * CDSTR + (ks - 4) * 32 + quad * 8];
        }
        v8s bf = *(const v8s*)bp;
        acc0[nt] = MFMA16(a0, bf, acc0[nt], 0, 0, 0);
        acc1[nt] = MFMA16(a1, bf, acc1[nt], 0, 0, 0);
      }
    }

    // ---- gates: ch = w*16 + quad*4 + r (pair ch, ch+64 lane-local) ----
    float ba[4], bb_[4];
    #pragma unroll
    for (int r = 0; r < 4; r++) { ba[r] = Bb[cha + r]; bb_[r] = Bb[64 + cha + r]; }
    #pragma unroll
    for (int nt = 0; nt < 4; nt++) {
      int t = nt * 16 + tl;
      v4s pk;
      #pragma unroll
      for (int r = 0; r < 4; r++) {
        float ia = acc0[nt][r] + ba[r];
        float ib = acc1[nt][r] + bb_[r];
        float ax = fabsf(ia);
        float e2 = __expf(-2.f * ax);
        float th = __builtin_copysignf((1.f - e2) / (1.f + e2), ia);
        float sg = 1.f / (1.f + __expf(-ib));
        pk[r] = (short)f2bf(th * sg);
      }
      *(v4s*)&Uact[t * ACSTR + cha] = pk;
    }
    __syncthreads();

    // ---- acts -> global (kfinal's deferred skip GEMM reads these) ----
    ushort_t* ab = actsb + (size_t)l * lstr + ((size_t)b * TT + t0) * 64;
    for (int e = tidx * 8; e < 4096; e += 2048) {
      int t = e >> 6, c = e & 63;
      *(v8s*)(ab + e) = *(const v8s*)&Uact[t * ACSTR + c];
    }

    if (!last) {
      // ---- stage 2: res GEMM + residual, Uxc updated IN PLACE ----
      v4f acc2[4];
      #pragma unroll
      for (int nt = 0; nt < 4; nt++) {
        v4f z;
        #pragma unroll
        for (int r = 0; r < 4; r++) z[r] = rb[cha + r];
        acc2[nt] = z;
      }
      #pragma unroll
      for (int ks = 0; ks < 2; ks++) {
        v8s a = *(const v8s*)(A2l + (((size_t)w * 2 + ks) * 64 + lane) * 8);
        #pragma unroll
        for (int nt = 0; nt < 4; nt++) {
          v8s bf = *(const v8s*)&Uact[(nt * 16 + tl) * ACSTR + ks * 32 + quad * 8];
          acc2[nt] = MFMA16(a, bf, acc2[nt], 0, 0, 0);
        }
      }
      #pragma unroll
      for (int nt = 0; nt < 4; nt++) {
        int t = nt * 16 + tl;
        v4s xo = *(const v4s*)&Uxc[t * XCSTR + cha];
        v4s nw;
        #pragma unroll
        for (int r = 0; r < 4; r++)
          nw[r] = (short)f2bf(acc2[nt][r] + bf2f((ushort_t)xo[r]));
        *(v4s*)&Uxc[t * XCSTR + cha] = nw;
      }
      __syncthreads();   // all channels updated before halo snapshot

      // ---- xout halo rows -> LLC via relaxed agent atomics ----
      int dnext = 1 << ((l + 1) & 7);
      int tmin = 64 - (dnext < 64 ? dnext : 64);
      ushort_t* xob = xoutg + ((size_t)b * TT + t0) * 64;
      for (int e = tidx * 8; e < 4096; e += 2048) {
        int t = e >> 6, c = e & 63;
        if (t >= tmin) {
          v8s v = *(const v8s*)&Uxc[t * XCSTR + c];
          u64_t w0, w1;
          __builtin_memcpy(&w0, &v, 8);
          __builtin_memcpy(&w1, ((const char*)&v) + 8, 8);
          u64_t* p = (u64_t*)(xob + e);
          __hip_atomic_store(p, w0, __ATOMIC_RELAXED, __HIP_MEMORY_SCOPE_AGENT);
          __hip_atomic_store(p + 1, w1, __ATOMIC_RELAXED, __HIP_MEMORY_SCOPE_AGENT);
        }
      }

      // ---- hierarchical grid barrier (shard arrive -> root -> release
      //      broadcast; pollers touch ONLY their shard's release line) ----
      __syncthreads();     // drains vmcnt: halo stores globally visible
      if (tidx == 0) {
        unsigned int* L = bar + l * BARSTR;
        int flat = b * 250 + blockIdx.x;           // 0..999
        int shard = flat & 15;                     // 0..7: 63 blks, 8..15: 62
        unsigned int tgt = (shard < 8) ? 62u : 61u;
        unsigned int old = __hip_atomic_fetch_add(L + shard * 32, 1u,
            __ATOMIC_RELAXED, __HIP_MEMORY_SCOPE_AGENT);
        if (old == tgt) {
          unsigned int ro = __hip_atomic_fetch_add(L + 16 * 32, 1u,
              __ATOMIC_RELAXED, __HIP_MEMORY_SCOPE_AGENT);
          if (ro == 15u) {
            #pragma unroll
            for (int s = 0; s < 16; s++)
              __hip_atomic_store(L + (17 + s) * 32, 1u,
                  __ATOMIC_RELAXED, __HIP_MEMORY_SCOPE_AGENT);
          }
        }
        while (__hip_atomic_load(L + (17 + shard) * 32,
            __ATOMIC_RELAXED, __HIP_MEMORY_SCOPE_AGENT) == 0u)
          __builtin_amdgcn_s_sleep(16);
      }
      __syncthreads();
    }
  }
}

// ---------------------------------------------------------------------------
// Final fused MFMA chain (r0 structure — measured 112 us). Skip GEMM
// (M=256, K=1024): acts tiles staged through double-buffered LDS, next-layer
// prefetch into NAMED registers, ONE barrier per layer. Then +SBsum -> relu
// -> out (K=256) -> relu -> end -> shift -> f32 store. LDS 33 KB -> 4 blk/CU.
// ---------------------------------------------------------------------------
__global__ __launch_bounds__(256) void kfinal(
    const ushort_t* __restrict__ actsb,
    const ushort_t* __restrict__ SWf, const ushort_t* __restrict__ OWf,
    const ushort_t* __restrict__ EWf, const float* __restrict__ SBsum,
    float* __restrict__ dout) {
  __shared__ ushort_t SMEM[64 * M3STR];   // 33 KB; skip-phase: AB dbuf, then M3
  int b = blockIdx.y;
  int t0 = blockIdx.x * 64;
  int tidx = threadIdx.x;
  int lane = tidx & 63;
  int w = tidx >> 6;
  int tl = lane & 15, quad = lane >> 4;

  // ---- skip GEMM, K = 16 layers * 64 ch ----
  v4f acc[4][4];
  #pragma unroll
  for (int mt = 0; mt < 4; mt++) {
    int o = (w * 4 + mt) * 16 + quad * 4;
    #pragma unroll
    for (int nt = 0; nt < 4; nt++) {
      v4f z;
      #pragma unroll
      for (int r = 0; r < 4; r++) z[r] = SBsum[o + r];
      acc[mt][nt] = z;
    }
  }
  const ushort_t* abase = actsb + ((size_t)b * TT + t0) * 64;
  const size_t lstr = (size_t)BB * TT * 64;
  int tq = tidx >> 2;               // t-row this thread copies (0..63)
  int pq = (tidx & 3) * 16;         // 16-short chunk within the row
  {  // preload layer 0 -> buffer 0
    const ushort_t* a0 = abase + tq * 64 + pq;
    v8s p0 = *(const v8s*)(a0);
    v8s p1 = *(const v8s*)(a0 + 8);
    *(v8s*)&SMEM[tq * ABSTR + pq] = p0;
    *(v8s*)&SMEM[tq * ABSTR + pq + 8] = p1;
  }
  __syncthreads();
  for (int l = 0; l < NLAYER; l++) {
    // prefetch next layer's tile into named regs (branchless: clamp index)
    int ln = (l + 1 < NLAYER) ? (l + 1) : (NLAYER - 1);
    const ushort_t* an = abase + (size_t)ln * lstr + tq * 64 + pq;
    v8s q0 = *(const v8s*)(an);
    v8s q1 = *(const v8s*)(an + 8);
    // compute layer l from LDS buffer l&1
    const ushort_t* ABc = SMEM + (l & 1) * (64 * ABSTR);
    #pragma unroll
    for (int ks2 = 0; ks2 < 2; ks2++) {
      int ksg = l * 2 + ks2;
      v8s bf[4];
      #pragma unroll
      for (int nt = 0; nt < 4; nt++)
        bf[nt] = *(const v8s*)&ABc[(nt * 16 + tl) * ABSTR + ks2 * 32 + quad * 8];
      #pragma unroll
      for (int mt = 0; mt < 4; mt++) {
        v8s a = *(const v8s*)(SWf + (((size_t)(w * 4 + mt) * 32 + ksg) * 64 + lane) * 8);
        #pragma unroll
        for (int nt = 0; nt < 4; nt++)
          acc[mt][nt] = MFMA16(a, bf[nt], acc[mt][nt], 0, 0, 0);
      }
    }
    // store prefetched tile into the other buffer (dead store at l=15)
    ushort_t* ABn = SMEM + ((l + 1) & 1) * (64 * ABSTR);
    *(v8s*)&ABn[tq * ABSTR + pq] = q0;
    *(v8s*)&ABn[tq * ABSTR + pq + 8] = q1;
    __syncthreads();
  }
  // ---- SMEM now reused as M3 [t][256+8] ----
  #pragma unroll
  for (int mt = 0; mt < 4; mt++) {
    int o = (w * 4 + mt) * 16 + quad * 4;
    #pragma unroll
    for (int nt = 0; nt < 4; nt++) {
      int t = nt * 16 + tl;
      #pragma unroll
      for (int r = 0; r < 4; r++)
        SMEM[t * M3STR + o + r] = f2bf(fmaxf(acc[mt][nt][r], 0.f));
    }
  }
  __syncthreads();

  // ---- out GEMM, K=256 ----
  v4f acc2[4][4];
  #pragma unroll
  for (int mt = 0; mt < 4; mt++)
    #pragma unroll
    for (int nt = 0; nt < 4; nt++) acc2[mt][nt] = 0.f;
  #pragma unroll
  for (int ks = 0; ks < 8; ks++) {
    v8s bf[4];
    #pragma unroll
    for (int nt = 0; nt < 4; nt++)
      bf[nt] = *(const v8s*)&SMEM[(nt * 16 + tl) * M3STR + ks * 32 + quad * 8];
    #pragma unroll
    for (int mt = 0; mt < 4; mt++) {
      v8s a = *(const v8s*)(OWf + (((size_t)(w * 4 + mt) * 8 + ks) * 64 + lane) * 8);
      #pragma unroll
      for (int nt = 0; nt < 4; nt++)
        acc2[mt][nt] = MFMA16(a, bf[nt], acc2[mt][nt], 0, 0, 0);
    }
  }
  __syncthreads();   // all M3 reads done before overwrite
  #pragma unroll
  for (int mt = 0; mt < 4; mt++) {
    int o = (w * 4 + mt) * 16 + quad * 4;
    #pragma unroll
    for (int nt = 0; nt < 4; nt++) {
      int t = nt * 16 + tl;
      #pragma unroll
      for (int r = 0; r < 4; r++)
        SMEM[t * M3STR + o + r] = f2bf(fmaxf(acc2[mt][nt][r], 0.f));
    }
  }
  __syncthreads();

  // ---- end GEMM, K=256, then shifted store ----
  v4f acc3[4][4];
  #pragma unroll
  for (int mt = 0; mt < 4; mt++)
    #pragma unroll
    for (int nt = 0; nt < 4; nt++) acc3[mt][nt] = 0.f;
  #pragma unroll
  for (int ks = 0; ks < 8; ks++) {
    v8s bf[4];
    #pragma unroll
    for (int nt = 0; nt < 4; nt++)
      bf[nt] = *(const v8s*)&SMEM[(nt * 16 + tl) * M3STR + ks * 32 + quad * 8];
    #pragma unroll
    for (int mt = 0; mt < 4; mt++) {
      v8s a = *(const v8s*)(EWf + (((size_t)(w * 4 + mt) * 8 + ks) * 64 + lane) * 8);
      #pragma unroll
      for (int nt = 0; nt < 4; nt++)
        acc3[mt][nt] = MFMA16(a, bf[nt], acc3[mt][nt], 0, 0, 0);
    }
  }
  #pragma unroll
  for (int mt = 0; mt < 4; mt++) {
    #pragma unroll
    for (int nt = 0; nt < 4; nt++) {
      int tg = t0 + nt * 16 + tl;
      #pragma unroll
      for (int r = 0; r < 4; r++) {
        int o = (w * 4 + mt) * 16 + quad * 4 + r;
        float* ob = dout + ((size_t)b * 256 + o) * TT;
        if (tg == 0) ob[0] = 0.f;
        if (tg + 1 < TT) ob[tg + 1] = acc3[mt][nt][r];
      }
    }
  }
}

// ---------------------------------------------------------------------------
extern "C" void kernel_launch(void* const* d_in, const int* in_sizes, int n_in,
                              void* d_out, int out_size, void* d_ws, size_t ws_size,
                              hipStream_t stream) {
  const float* feat   = (const float*)d_in[0];
  const int*   fin    = (const int*)d_in[1];
  const float* embed  = (const float*)d_in[2];
  const float* up_w   = (const float*)d_in[3];
  const float* up_b   = (const float*)d_in[4];
  const float* cond_w = (const float*)d_in[5];
  const float* cond_b = (const float*)d_in[6];
  const float* dil_w  = (const float*)d_in[7];
  const float* dil_b  = (const float*)d_in[8];
  const float* res_w  = (const float*)d_in[9];
  const float* res_b  = (const float*)d_in[10];
  const float* skip_w = (const float*)d_in[11];
  const float* skip_b = (const float*)d_in[12];
  const float* out_w  = (const float*)d_in[13];
  const float* end_w  = (const float*)d_in[14];

  // Workspace (~175 MB).
  float* ws = (float*)d_ws;
  unsigned int* bar = (unsigned int*)ws;          // barrier state
  size_t off = BARSZ;
  float* Bcomb = ws + off; off += NLAYER * 128;
  float* SBsum = ws + off; off += 256;
  ushort_t* ub = (ushort_t*)(ws + off);
  size_t uo = 0;
  ushort_t* A1   = ub + uo; uo += A1SZ;
  ushort_t* A2   = ub + uo; uo += A2SZ;
  ushort_t* SWf  = ub + uo; uo += SWSZ;
  ushort_t* OWf  = ub + uo; uo += OWSZ;
  ushort_t* EWf  = ub + uo; uo += OWSZ;
  ushort_t* Aup  = ub + uo; uo += AUPSZ;
  ushort_t* Bup  = ub + uo; uo += BUPSZ;
  ushort_t* cond = ub + uo; uo += (size_t)BB * TT * 80;
  ushort_t* x0   = ub + uo; uo += (size_t)BB * TT * 64;
  ushort_t* x1   = ub + uo; uo += (size_t)BB * TT * 64;
  ushort_t* acts = ub + uo; uo += (size_t)NLAYER * BB * TT * 64;  // 131 MB

  kprep<<<1024, 256, 0, stream>>>(feat, fin, embed, up_w, cond_w, cond_b,
      dil_w, dil_b, res_w, skip_w, skip_b, out_w, end_w,
      A1, A2, SWf, OWf, EWf, Aup, Bup, x0, Bcomb, SBsum, bar);
  kup<<<250, 256, 0, stream>>>(Aup, Bup, up_b, cond);
  kchain<<<dim3(250, BB), 256, 0, stream>>>(x0, x1, cond, acts,
      A1, A2, Bcomb, res_b, bar);
  kfinal<<<dim3(250, BB), 256, 0, stream>>>(acts, SWf, OWf, EWf, SBsum,
      (float*)d_out);
}

// Round 8
// 431.359 us; speedup vs baseline: 1.2703x; 1.0829x over previous
//
#include <hip/hip_runtime.h>
#include <hip/hip_bf16.h>

#define TT 16000
#define BB 4
#define NLAYER 16
#define NBLK 1000    // kchain grid = 250 x 4; ALL co-resident (4 blk/CU x 256 CU = 1024)
#define BARSTR 1088  // u32 per layer-barrier: 34 lines (16 shard + root + 16 release + pad)
#define BARSZ (15 * BARSTR)
#define XCSTR 72    // kchain x-current tile row stride (shorts): 64 + 8
#define XPSTR 72    // kchain halo tile row stride
#define ACSTR 72    // kchain acts row stride
#define CDSTR 88    // kchain cond row stride (80 + 8 pad; ks6 tail reads pad/next row, finite & A=0)
#define M3STR 264   // kfinal mid row stride (shorts): 256 + 8 pad
#define ABSTR 72    // kfinal acts-stage row stride (shorts): 64 + 8 pad

#define A1SZ (NLAYER*8*7*512)   // gate-weight A-frags
#define A2SZ (NLAYER*4*2*512)   // res-weight A-frags
#define SWSZ (16*32*512)        // skip-weight A-frags (M=256, K=1024)
#define OWSZ (16*8*512)         // out/end-weight A-frags (M=256, K=256)
#define AUPSZ (20*10*512)       // upsample A-frags (M=320, K=320)
#define BUPSZ (1000*10*512)     // upsample B-frags (K=320, N=16000)

typedef unsigned short ushort_t;
typedef unsigned long long u64_t;
typedef short v8s __attribute__((ext_vector_type(8)));
typedef short v4s __attribute__((ext_vector_type(4)));
typedef float v4f __attribute__((ext_vector_type(4)));

#define MFMA16 __builtin_amdgcn_mfma_f32_16x16x32_bf16

__device__ __forceinline__ float bf2f(ushort_t u) {
  unsigned int x = ((unsigned int)u) << 16;
  float f; __builtin_memcpy(&f, &x, 4); return f;
}
__device__ __forceinline__ ushort_t f2bf(float f) {
  unsigned int x; __builtin_memcpy(&x, &f, 4);
  x += 0x7fffu + ((x >> 16) & 1u);   // RNE
  return (ushort_t)(x >> 16);
}

// ---------------------------------------------------------------------------
// Prep: pack every weight matrix into exact MFMA fragment order (bf16).
// A-frag: elem j of lane l = A[m = mt*16 + (l&15)][k = ks*32 + (l>>4)*8 + j]
// B-frag: elem j of lane l = B[k = ks*32 + (l>>4)*8 + j][n = nt*16 + (l&15)]
// Also: embed gather -> x0, upsample operands Aup/Bup, barrier zeroing.
// (Bup mapping: r0 original — reads are 64B-coalesced per 16-lane group,
// writes linear. The r7 "read-linear" rewrite scattered the writes; reverted.)
// ---------------------------------------------------------------------------
__global__ __launch_bounds__(256) void kprep(
    const float* __restrict__ feat, const int* __restrict__ fin,
    const float* __restrict__ embed, const float* __restrict__ up_w,
    const float* __restrict__ cond_w, const float* __restrict__ cond_b,
    const float* __restrict__ dil_w, const float* __restrict__ dil_b,
    const float* __restrict__ res_w, const float* __restrict__ skip_w,
    const float* __restrict__ skip_b, const float* __restrict__ out_w,
    const float* __restrict__ end_w,
    ushort_t* __restrict__ A1, ushort_t* __restrict__ A2,
    ushort_t* __restrict__ SWf, ushort_t* __restrict__ OWf,
    ushort_t* __restrict__ EWf, ushort_t* __restrict__ Aup,
    ushort_t* __restrict__ Bup, ushort_t* __restrict__ x0,
    float* __restrict__ Bcomb, float* __restrict__ SBsum,
    unsigned int* __restrict__ bar) {
  int tid = blockIdx.x * 256 + threadIdx.x;
  int np = gridDim.x * 256;
  // zero the kchain grid-barrier state (re-zeroed every iteration/replay)
  for (int idx = tid; idx < BARSZ; idx += np) bar[idx] = 0u;
  // A1: gate GEMM [16 layers][8 Mtiles][7 Ksteps][64 lanes][8]
  // K rows: 0..63 = xc (tap1), 64..127 = xp (tap0), 128..207 = cond, pad=0
  for (int idx = tid; idx < A1SZ; idx += np) {
    int j = idx & 7, lane = (idx >> 3) & 63;
    int r_ = idx >> 9;
    int ks = r_ % 7; int r2 = r_ / 7;
    int mt = r2 & 7; int i = r2 >> 3;
    int m = mt * 16 + (lane & 15);
    int k = ks * 32 + (lane >> 4) * 8 + j;
    float v = 0.f;
    if (k < 64)       v = dil_w[((i * 128 + m) * 64 + k) * 2 + 1];
    else if (k < 128) v = dil_w[((i * 128 + m) * 64 + (k - 64)) * 2 + 0];
    else if (k < 208) v = cond_w[(i * 128 + m) * 80 + (k - 128)];
    A1[idx] = f2bf(v);
  }
  // A2: res GEMM [16][4 Mtiles][2 Ksteps][64][8] (layer 15 zeroed/unused)
  for (int idx = tid; idx < A2SZ; idx += np) {
    int j = idx & 7, lane = (idx >> 3) & 63;
    int r_ = idx >> 9;
    int ks = r_ & 1; int mt = (r_ >> 1) & 3; int i = r_ >> 3;
    int m = mt * 16 + (lane & 15);
    int k = ks * 32 + (lane >> 4) * 8 + j;
    A2[idx] = f2bf(i < 15 ? res_w[(i * 64 + m) * 64 + k] : 0.f);
  }
  // SWf: skip GEMM [16 Mtiles][32 Ksteps][64][8], K = layer*64 + ch
  for (int idx = tid; idx < SWSZ; idx += np) {
    int j = idx & 7, lane = (idx >> 3) & 63;
    int r_ = idx >> 9;
    int ks = r_ & 31; int mt = r_ >> 5;
    int m = mt * 16 + (lane & 15);
    int k = ks * 32 + (lane >> 4) * 8 + j;
    int i = k >> 6, ch = k & 63;
    SWf[idx] = f2bf(skip_w[(i * 256 + m) * 64 + ch]);
  }
  // OWf/EWf: [16 Mtiles][8 Ksteps][64][8]
  for (int idx = tid; idx < OWSZ; idx += np) {
    int j = idx & 7, lane = (idx >> 3) & 63;
    int r_ = idx >> 9;
    int ks = r_ & 7; int mt = r_ >> 3;
    int m = mt * 16 + (lane & 15);
    int k = ks * 32 + (lane >> 4) * 8 + j;
    OWf[idx] = f2bf(out_w[m * 256 + k]);
    EWf[idx] = f2bf(end_w[m * 256 + k]);
  }
  // Aup: [20 Mtiles][10 Ks][64][8]; A[mrow=(b*80+q)][km=(m*80+i)] =
  //   feat[b,i,q-m] (0 if q<m)
  for (int idx = tid; idx < AUPSZ; idx += np) {
    int j = idx & 7, lane = (idx >> 3) & 63;
    int r_ = idx >> 9;
    int ks = r_ % 10; int mt = r_ / 10;
    int mrow = mt * 16 + (lane & 15);
    int km = ks * 32 + (lane >> 4) * 8 + j;
    int b = mrow / 80, q = mrow % 80;
    int m = km / 80, i = km % 80;
    int jj = q - m;
    Aup[idx] = f2bf(jj >= 0 ? feat[(b * 80 + i) * 80 + jj] : 0.f);
  }
  // Bup: [1000 Ntiles][10 Ks][64][8]; B[km][col=(o*200+r)] =
  //   up_w[i, o, 200m + r]  (16 consecutive lanes read 16 consecutive floats)
  for (int idx = tid; idx < BUPSZ; idx += np) {
    int j = idx & 7, lane = (idx >> 3) & 63;
    int r_ = idx >> 9;
    int ks = r_ % 10; int nt = r_ / 10;
    int km = ks * 32 + (lane >> 4) * 8 + j;
    int m = km / 80, i = km % 80;
    int col = nt * 16 + (lane & 15);
    int o = col / 200, r = col % 200;
    Bup[idx] = f2bf(up_w[(size_t)(i * 80 + o) * 800 + m * 200 + r]);
  }
  // embed gather: x0[b][t][ch] bf16
  for (int idx = tid; idx < BB * TT * 64; idx += np) {
    int k = idx & 63;
    int bt = idx >> 6;            // b*TT + t
    x0[idx] = f2bf(embed[fin[bt] * 64 + k]);
  }
  for (int idx = tid; idx < NLAYER * 128; idx += np)
    Bcomb[idx] = dil_b[idx] + cond_b[idx];
  for (int idx = tid; idx < 256; idx += np) {
    float s = 0.f;
    for (int i = 0; i < NLAYER; i++) s += skip_b[i * 256 + idx];
    SBsum[idx] = s;
  }
}

// ---------------------------------------------------------------------------
// Upsample GEMM, MFMA: M=320 (b,q), K=320 (m,i), N=16000 (o*200+r).
// ---------------------------------------------------------------------------
__global__ __launch_bounds__(256) void kup(
    const ushort_t* __restrict__ Aup, const ushort_t* __restrict__ Bup,
    const float* __restrict__ up_b, ushort_t* __restrict__ cond) {
  int nt0 = blockIdx.x * 4;
  int lane = threadIdx.x & 63;
  int w = threadIdx.x >> 6;
  int tl = lane & 15, quad = lane >> 4;
  v4f acc[5][4];
  #pragma unroll
  for (int mt = 0; mt < 5; mt++)
    #pragma unroll
    for (int nt = 0; nt < 4; nt++) acc[mt][nt] = 0.f;
  #pragma unroll
  for (int ks = 0; ks < 10; ks++) {
    v8s bf[4];
    #pragma unroll
    for (int nt = 0; nt < 4; nt++)
      bf[nt] = *(const v8s*)(Bup + (((size_t)(nt0 + nt) * 10 + ks) * 64 + lane) * 8);
    #pragma unroll
    for (int mt = 0; mt < 5; mt++) {
      v8s a = *(const v8s*)(Aup + (((size_t)(w * 5 + mt) * 10 + ks) * 64 + lane) * 8);
      #pragma unroll
      for (int nt = 0; nt < 4; nt++)
        acc[mt][nt] = MFMA16(a, bf[nt], acc[mt][nt], 0, 0, 0);
    }
  }
  #pragma unroll
  for (int mt = 0; mt < 5; mt++) {
    #pragma unroll
    for (int nt = 0; nt < 4; nt++) {
      int col = (nt0 + nt) * 16 + tl;
      int o = col / 200, r = col % 200;
      float bias = up_b[o];
      #pragma unroll
      for (int rg = 0; rg < 4; rg++) {
        int mrow = (w * 5 + mt) * 16 + quad * 4 + rg;
        int b = mrow / 80, q = mrow % 80;
        cond[((size_t)b * TT + q * 200 + r) * 80 + o] = f2bf(acc[mt][nt][rg] + bias);
      }
    }
  }
}

// ---------------------------------------------------------------------------
// Fused 16-layer WaveNet chain — byte-identical to r7 (197 us measured):
// no Uxp bulk copy (per-lane Uxc[t-d]/Uhalo select), hierarchical barrier
// (shard arrive -> root -> per-shard release lines), relaxed agent atomics
// only (LLC-coherent, zero cache-maintenance ops).
// ---------------------------------------------------------------------------
__global__ __launch_bounds__(256, 4) void kchain(
    ushort_t* __restrict__ x0g, ushort_t* __restrict__ x1g,
    const ushort_t* __restrict__ cond, ushort_t* __restrict__ actsb,
    const ushort_t* __restrict__ A1, const ushort_t* __restrict__ A2,
    const float* __restrict__ Bcomb, const float* __restrict__ resb,
    unsigned int* __restrict__ bar) {
  __shared__ ushort_t Uxc[64 * XCSTR];       // 9.0 KB current x tile
  __shared__ ushort_t Uhalo[64 * XPSTR];     // 9.0 KB halo rows (t < d)
  __shared__ ushort_t Uact[64 * ACSTR];      // 9.0 KB gate acts
  __shared__ ushort_t Ucd[64 * CDSTR + 8];   // 11.0 KB cond tile (+tail pad)
  int b = blockIdx.y;
  int t0 = blockIdx.x * 64;
  int tidx = threadIdx.x;
  int lane = tidx & 63;
  int w = tidx >> 6;
  int tl = lane & 15, quad = lane >> 4;
  int cha = w * 16 + quad * 4;
  const size_t lstr = (size_t)BB * TT * 64;

  // ---- one-time stage: Uxc <- x0, Ucd <- cond, zero cond pad ----
  const ushort_t* xb0 = x0g + ((size_t)b * TT + t0) * 64;
  for (int e = tidx * 8; e < 4096; e += 2048) {
    int t = e >> 6, c = e & 63;
    *(v8s*)&Uxc[t * XCSTR + c] = *(const v8s*)(xb0 + e);
  }
  const ushort_t* cbp = cond + ((size_t)b * TT + t0) * 80;
  for (int e = tidx * 8; e < 5120; e += 2048) {
    int t = e / 80, c = e - t * 80;
    *(v8s*)&Ucd[t * CDSTR + c] = *(const v8s*)(cbp + e);
  }
  // zero pad cols 80..87 every row + 8 tail shorts (ks6 reads must be finite)
  for (int e2 = tidx; e2 < 520; e2 += 256) {
    if (e2 < 512) Ucd[(e2 >> 3) * CDSTR + 80 + (e2 & 7)] = 0;
    else          Ucd[64 * CDSTR + (e2 - 512)] = 0;
  }
  __syncthreads();

  for (int l = 0; l < NLAYER; l++) {
    int d = 1 << (l & 7);
    int hr = (d < 64) ? d : 64;                 // halo rows staged this layer
    const ushort_t* xing = (l & 1) ? x1g : x0g;
    ushort_t* xoutg = (l & 1) ? x0g : x1g;
    const ushort_t* A1l = A1 + (size_t)l * 8 * 7 * 512;
    const ushort_t* A2l = A2 + (size_t)l * 4 * 2 * 512;
    const float* Bb = Bcomb + l * 128;
    const float* rb = resb + (l < 15 ? l : 0) * 64;
    int last = (l == NLAYER - 1);

    // ---- stage Uhalo: ONLY rows t<hr, from left neighbor (LLC atomics) ----
    for (int e = tidx * 8; e < hr * 64; e += 2048) {
      int t = e >> 6, c = e & 63;
      int tp = t0 + t - d;
      v8s v = (v8s)0;
      if (tp >= 0) {
        const u64_t* p = (const u64_t*)(xing + ((size_t)b * TT + tp) * 64 + c);
        u64_t w0 = __hip_atomic_load(p, __ATOMIC_RELAXED, __HIP_MEMORY_SCOPE_AGENT);
        u64_t w1 = __hip_atomic_load(p + 1, __ATOMIC_RELAXED, __HIP_MEMORY_SCOPE_AGENT);
        __builtin_memcpy(&v, &w0, 8);
        __builtin_memcpy(((char*)&v) + 8, &w1, 8);
      }
      *(v8s*)&Uhalo[t * XPSTR + c] = v;
    }
    __syncthreads();

    // ---- stage 1: gate GEMM (xc from Uxc rows t; xp from Uxc[t-d] or
    //      Uhalo[t]; cond from Ucd) ----
    v4f acc0[4], acc1[4];
    #pragma unroll
    for (int nt = 0; nt < 4; nt++) { acc0[nt] = 0.f; acc1[nt] = 0.f; }
    #pragma unroll
    for (int ks = 0; ks < 7; ks++) {
      v8s a0 = *(const v8s*)(A1l + (((size_t)w * 7 + ks) * 64 + lane) * 8);
      v8s a1 = *(const v8s*)(A1l + (((size_t)(w + 4) * 7 + ks) * 64 + lane) * 8);
      #pragma unroll
      for (int nt = 0; nt < 4; nt++) {
        int t = nt * 16 + tl;
        const ushort_t* bp;
        if (ks < 2) {
          bp = &Uxc[t * XCSTR + ks * 32 + quad * 8];
        } else if (ks < 4) {
          int toff = t - d;
          bp = (toff >= 0) ? &Uxc[toff * XCSTR + (ks - 2) * 32 + quad * 8]
                           : &Uhalo[t * XPSTR + (ks - 2) * 32 + quad * 8];
        } else {
          bp = &Ucd[t * CDSTR + (ks - 4) * 32 + quad * 8];
        }
        v8s bf = *(const v8s*)bp;
        acc0[nt] = MFMA16(a0, bf, acc0[nt], 0, 0, 0);
        acc1[nt] = MFMA16(a1, bf, acc1[nt], 0, 0, 0);
      }
    }

    // ---- gates: ch = w*16 + quad*4 + r (pair ch, ch+64 lane-local) ----
    float ba[4], bb_[4];
    #pragma unroll
    for (int r = 0; r < 4; r++) { ba[r] = Bb[cha + r]; bb_[r] = Bb[64 + cha + r]; }
    #pragma unroll
    for (int nt = 0; nt < 4; nt++) {
      int t = nt * 16 + tl;
      v4s pk;
      #pragma unroll
      for (int r = 0; r < 4; r++) {
        float ia = acc0[nt][r] + ba[r];
        float ib = acc1[nt][r] + bb_[r];
        float ax = fabsf(ia);
        float e2 = __expf(-2.f * ax);
        float th = __builtin_copysignf((1.f - e2) / (1.f + e2), ia);
        float sg = 1.f / (1.f + __expf(-ib));
        pk[r] = (short)f2bf(th * sg);
      }
      *(v4s*)&Uact[t * ACSTR + cha] = pk;
    }
    __syncthreads();

    // ---- acts -> global (kfinal's deferred skip GEMM reads these) ----
    ushort_t* ab = actsb + (size_t)l * lstr + ((size_t)b * TT + t0) * 64;
    for (int e = tidx * 8; e < 4096; e += 2048) {
      int t = e >> 6, c = e & 63;
      *(v8s*)(ab + e) = *(const v8s*)&Uact[t * ACSTR + c];
    }

    if (!last) {
      // ---- stage 2: res GEMM + residual, Uxc updated IN PLACE ----
      v4f acc2[4];
      #pragma unroll
      for (int nt = 0; nt < 4; nt++) {
        v4f z;
        #pragma unroll
        for (int r = 0; r < 4; r++) z[r] = rb[cha + r];
        acc2[nt] = z;
      }
      #pragma unroll
      for (int ks = 0; ks < 2; ks++) {
        v8s a = *(const v8s*)(A2l + (((size_t)w * 2 + ks) * 64 + lane) * 8);
        #pragma unroll
        for (int nt = 0; nt < 4; nt++) {
          v8s bf = *(const v8s*)&Uact[(nt * 16 + tl) * ACSTR + ks * 32 + quad * 8];
          acc2[nt] = MFMA16(a, bf, acc2[nt], 0, 0, 0);
        }
      }
      #pragma unroll
      for (int nt = 0; nt < 4; nt++) {
        int t = nt * 16 + tl;
        v4s xo = *(const v4s*)&Uxc[t * XCSTR + cha];
        v4s nw;
        #pragma unroll
        for (int r = 0; r < 4; r++)
          nw[r] = (short)f2bf(acc2[nt][r] + bf2f((ushort_t)xo[r]));
        *(v4s*)&Uxc[t * XCSTR + cha] = nw;
      }
      __syncthreads();   // all channels updated before halo snapshot

      // ---- xout halo rows -> LLC via relaxed agent atomics ----
      int dnext = 1 << ((l + 1) & 7);
      int tmin = 64 - (dnext < 64 ? dnext : 64);
      ushort_t* xob = xoutg + ((size_t)b * TT + t0) * 64;
      for (int e = tidx * 8; e < 4096; e += 2048) {
        int t = e >> 6, c = e & 63;
        if (t >= tmin) {
          v8s v = *(const v8s*)&Uxc[t * XCSTR + c];
          u64_t w0, w1;
          __builtin_memcpy(&w0, &v, 8);
          __builtin_memcpy(&w1, ((const char*)&v) + 8, 8);
          u64_t* p = (u64_t*)(xob + e);
          __hip_atomic_store(p, w0, __ATOMIC_RELAXED, __HIP_MEMORY_SCOPE_AGENT);
          __hip_atomic_store(p + 1, w1, __ATOMIC_RELAXED, __HIP_MEMORY_SCOPE_AGENT);
        }
      }

      // ---- hierarchical grid barrier (shard arrive -> root -> release
      //      broadcast; pollers touch ONLY their shard's release line) ----
      __syncthreads();     // drains vmcnt: halo stores globally visible
      if (tidx == 0) {
        unsigned int* L = bar + l * BARSTR;
        int flat = b * 250 + blockIdx.x;           // 0..999
        int shard = flat & 15;                     // 0..7: 63 blks, 8..15: 62
        unsigned int tgt = (shard < 8) ? 62u : 61u;
        unsigned int old = __hip_atomic_fetch_add(L + shard * 32, 1u,
            __ATOMIC_RELAXED, __HIP_MEMORY_SCOPE_AGENT);
        if (old == tgt) {
          unsigned int ro = __hip_atomic_fetch_add(L + 16 * 32, 1u,
              __ATOMIC_RELAXED, __HIP_MEMORY_SCOPE_AGENT);
          if (ro == 15u) {
            #pragma unroll
            for (int s = 0; s < 16; s++)
              __hip_atomic_store(L + (17 + s) * 32, 1u,
                  __ATOMIC_RELAXED, __HIP_MEMORY_SCOPE_AGENT);
          }
        }
        while (__hip_atomic_load(L + (17 + shard) * 32,
            __ATOMIC_RELAXED, __HIP_MEMORY_SCOPE_AGENT) == 0u)
          __builtin_amdgcn_s_sleep(16);
      }
      __syncthreads();
    }
  }
}

// ---------------------------------------------------------------------------
// Final fused MFMA chain — DEPTH-2 register prefetch pipeline.
// r0's structure issued layer l+1's loads at layer l's start and consumed
// them (ds_write) at layer l's end: ~8.2 KB outstanding/block -> measured
// 1.3 TB/s aggregate = the 112 us. Here TWO named reg sets (qa, qb) hold
// tiles l+1 and l+2; the tile written to LDS at layer l was loaded at layer
// l-2, so its (register-tracked, counted) vmcnt wait is already satisfied
// and a second tile stays in flight across the barrier. Outstanding bytes
// double -> expect ~2x the streaming rate. 2-layer unrolled loop, static
// buffer parity (buf0 = even layers). Then +SBsum -> relu -> out (K=256)
// -> relu -> end -> shift -> f32 store. LDS 33 KB.
// ---------------------------------------------------------------------------
#define KF_COMPUTE(L, BUF)                                                    \
  {                                                                           \
    _Pragma("unroll")                                                         \
    for (int ks2 = 0; ks2 < 2; ks2++) {                                       \
      int ksg = (L) * 2 + ks2;                                                \
      v8s bf[4];                                                              \
      _Pragma("unroll")                                                       \
      for (int nt = 0; nt < 4; nt++)                                          \
        bf[nt] = *(const v8s*)&(BUF)[(nt * 16 + tl) * ABSTR + ks2 * 32 +      \
                                     quad * 8];                               \
      _Pragma("unroll")                                                       \
      for (int mt = 0; mt < 4; mt++) {                                        \
        v8s a = *(const v8s*)(SWf +                                           \
            (((size_t)(w * 4 + mt) * 32 + ksg) * 64 + lane) * 8);             \
        _Pragma("unroll")                                                     \
        for (int nt = 0; nt < 4; nt++)                                        \
          acc[mt][nt] = MFMA16(a, bf[nt], acc[mt][nt], 0, 0, 0);              \
      }                                                                       \
    }                                                                         \
  }

__global__ __launch_bounds__(256) void kfinal(
    const ushort_t* __restrict__ actsb,
    const ushort_t* __restrict__ SWf, const ushort_t* __restrict__ OWf,
    const ushort_t* __restrict__ EWf, const float* __restrict__ SBsum,
    float* __restrict__ dout) {
  __shared__ ushort_t SMEM[64 * M3STR];   // 33 KB; skip-phase: AB dbuf, then M3
  int b = blockIdx.y;
  int t0 = blockIdx.x * 64;
  int tidx = threadIdx.x;
  int lane = tidx & 63;
  int w = tidx >> 6;
  int tl = lane & 15, quad = lane >> 4;

  // ---- skip GEMM, K = 16 layers * 64 ch ----
  v4f acc[4][4];
  #pragma unroll
  for (int mt = 0; mt < 4; mt++) {
    int o = (w * 4 + mt) * 16 + quad * 4;
    #pragma unroll
    for (int nt = 0; nt < 4; nt++) {
      v4f z;
      #pragma unroll
      for (int r = 0; r < 4; r++) z[r] = SBsum[o + r];
      acc[mt][nt] = z;
    }
  }
  const size_t lstr = (size_t)BB * TT * 64;
  int tq = tidx >> 2;               // t-row this thread copies (0..63)
  int pq = (tidx & 3) * 16;         // 16-short chunk within the row
  const ushort_t* a0p = actsb + ((size_t)b * TT + t0) * 64 + tq * 64 + pq;
  {  // stage layer 0 -> buffer 0
    v8s p0 = *(const v8s*)(a0p);
    v8s p1 = *(const v8s*)(a0p + 8);
    *(v8s*)&SMEM[tq * ABSTR + pq] = p0;
    *(v8s*)&SMEM[tq * ABSTR + pq + 8] = p1;
  }
  // issue prefetches: qa = acts(1), qb = acts(2) — both in flight
  v8s qa0 = *(const v8s*)(a0p + 1 * lstr);
  v8s qa1 = *(const v8s*)(a0p + 1 * lstr + 8);
  v8s qb0 = *(const v8s*)(a0p + 2 * lstr);
  v8s qb1 = *(const v8s*)(a0p + 2 * lstr + 8);
  __syncthreads();
  for (int l = 0; l < NLAYER; l += 2) {
    // ---- even layer l: compute from buf0 ----
    KF_COMPUTE(l, SMEM);
    // buf1 <- qa (acts l+1; loaded >=2 layers ago), reissue qa <- acts(l+3)
    *(v8s*)&SMEM[64 * ABSTR + tq * ABSTR + pq] = qa0;
    *(v8s*)&SMEM[64 * ABSTR + tq * ABSTR + pq + 8] = qa1;
    {
      int ln = (l + 3 < NLAYER) ? (l + 3) : (NLAYER - 1);
      qa0 = *(const v8s*)(a0p + (size_t)ln * lstr);
      qa1 = *(const v8s*)(a0p + (size_t)ln * lstr + 8);
    }
    __syncthreads();
    // ---- odd layer l+1: compute from buf1 ----
    KF_COMPUTE(l + 1, SMEM + 64 * ABSTR);
    // buf0 <- qb (acts l+2; dead at l=14), reissue qb <- acts(l+4)
    *(v8s*)&SMEM[tq * ABSTR + pq] = qb0;
    *(v8s*)&SMEM[tq * ABSTR + pq + 8] = qb1;
    {
      int ln = (l + 4 < NLAYER) ? (l + 4) : (NLAYER - 1);
      qb0 = *(const v8s*)(a0p + (size_t)ln * lstr);
      qb1 = *(const v8s*)(a0p + (size_t)ln * lstr + 8);
    }
    __syncthreads();
  }
  // ---- SMEM now reused as M3 [t][256+8] ----
  #pragma unroll
  for (int mt = 0; mt < 4; mt++) {
    int o = (w * 4 + mt) * 16 + quad * 4;
    #pragma unroll
    for (int nt = 0; nt < 4; nt++) {
      int t = nt * 16 + tl;
      #pragma unroll
      for (int r = 0; r < 4; r++)
        SMEM[t * M3STR + o + r] = f2bf(fmaxf(acc[mt][nt][r], 0.f));
    }
  }
  __syncthreads();

  // ---- out GEMM, K=256 ----
  v4f acc2[4][4];
  #pragma unroll
  for (int mt = 0; mt < 4; mt++)
    #pragma unroll
    for (int nt = 0; nt < 4; nt++) acc2[mt][nt] = 0.f;
  #pragma unroll
  for (int ks = 0; ks < 8; ks++) {
    v8s bf[4];
    #pragma unroll
    for (int nt = 0; nt < 4; nt++)
      bf[nt] = *(const v8s*)&SMEM[(nt * 16 + tl) * M3STR + ks * 32 + quad * 8];
    #pragma unroll
    for (int mt = 0; mt < 4; mt++) {
      v8s a = *(const v8s*)(OWf + (((size_t)(w * 4 + mt) * 8 + ks) * 64 + lane) * 8);
      #pragma unroll
      for (int nt = 0; nt < 4; nt++)
        acc2[mt][nt] = MFMA16(a, bf[nt], acc2[mt][nt], 0, 0, 0);
    }
  }
  __syncthreads();   // all M3 reads done before overwrite
  #pragma unroll
  for (int mt = 0; mt < 4; mt++) {
    int o = (w * 4 + mt) * 16 + quad * 4;
    #pragma unroll
    for (int nt = 0; nt < 4; nt++) {
      int t = nt * 16 + tl;
      #pragma unroll
      for (int r = 0; r < 4; r++)
        SMEM[t * M3STR + o + r] = f2bf(fmaxf(acc2[mt][nt][r], 0.f));
    }
  }
  __syncthreads();

  // ---- end GEMM, K=256, then shifted store ----
  v4f acc3[4][4];
  #pragma unroll
  for (int mt = 0; mt < 4; mt++)
    #pragma unroll
    for (int nt = 0; nt < 4; nt++) acc3[mt][nt] = 0.f;
  #pragma unroll
  for (int ks = 0; ks < 8; ks++) {
    v8s bf[4];
    #pragma unroll
    for (int nt = 0; nt < 4; nt++)
      bf[nt] = *(const v8s*)&SMEM[(nt * 16 + tl) * M3STR + ks * 32 + quad * 8];
    #pragma unroll
    for (int mt = 0; mt < 4; mt++) {
      v8s a = *(const v8s*)(EWf + (((size_t)(w * 4 + mt) * 8 + ks) * 64 + lane) * 8);
      #pragma unroll
      for (int nt = 0; nt < 4; nt++)
        acc3[mt][nt] = MFMA16(a, bf[nt], acc3[mt][nt], 0, 0, 0);
    }
  }
  #pragma unroll
  for (int mt = 0; mt < 4; mt++) {
    #pragma unroll
    for (int nt = 0; nt < 4; nt++) {
      int tg = t0 + nt * 16 + tl;
      #pragma unroll
      for (int r = 0; r < 4; r++) {
        int o = (w * 4 + mt) * 16 + quad * 4 + r;
        float* ob = dout + ((size_t)b * 256 + o) * TT;
        if (tg == 0) ob[0] = 0.f;
        if (tg + 1 < TT) ob[tg + 1] = acc3[mt][nt][r];
      }
    }
  }
}

// ---------------------------------------------------------------------------
extern "C" void kernel_launch(void* const* d_in, const int* in_sizes, int n_in,
                              void* d_out, int out_size, void* d_ws, size_t ws_size,
                              hipStream_t stream) {
  const float* feat   = (const float*)d_in[0];
  const int*   fin    = (const int*)d_in[1];
  const float* embed  = (const float*)d_in[2];
  const float* up_w   = (const float*)d_in[3];
  const float* up_b   = (const float*)d_in[4];
  const float* cond_w = (const float*)d_in[5];
  const float* cond_b = (const float*)d_in[6];
  const float* dil_w  = (const float*)d_in[7];
  const float* dil_b  = (const float*)d_in[8];
  const float* res_w  = (const float*)d_in[9];
  const float* res_b  = (const float*)d_in[10];
  const float* skip_w = (const float*)d_in[11];
  const float* skip_b = (const float*)d_in[12];
  const float* out_w  = (const float*)d_in[13];
  const float* end_w  = (const float*)d_in[14];

  // Workspace (~175 MB).
  float* ws = (float*)d_ws;
  unsigned int* bar = (unsigned int*)ws;          // barrier state
  size_t off = BARSZ;
  float* Bcomb = ws + off; off += NLAYER * 128;
  float* SBsum = ws + off; off += 256;
  ushort_t* ub = (ushort_t*)(ws + off);
  size_t uo = 0;
  ushort_t* A1   = ub + uo; uo += A1SZ;
  ushort_t* A2   = ub + uo; uo += A2SZ;
  ushort_t* SWf  = ub + uo; uo += SWSZ;
  ushort_t* OWf  = ub + uo; uo += OWSZ;
  ushort_t* EWf  = ub + uo; uo += OWSZ;
  ushort_t* Aup  = ub + uo; uo += AUPSZ;
  ushort_t* Bup  = ub + uo; uo += BUPSZ;
  ushort_t* cond = ub + uo; uo += (size_t)BB * TT * 80;
  ushort_t* x0   = ub + uo; uo += (size_t)BB * TT * 64;
  ushort_t* x1   = ub + uo; uo += (size_t)BB * TT * 64;
  ushort_t* acts = ub + uo; uo += (size_t)NLAYER * BB * TT * 64;  // 131 MB

  kprep<<<1024, 256, 0, stream>>>(feat, fin, embed, up_w, cond_w, cond_b,
      dil_w, dil_b, res_w, skip_w, skip_b, out_w, end_w,
      A1, A2, SWf, OWf, EWf, Aup, Bup, x0, Bcomb, SBsum, bar);
  kup<<<250, 256, 0, stream>>>(Aup, Bup, up_b, cond);
  kchain<<<dim3(250, BB), 256, 0, stream>>>(x0, x1, cond, acts,
      A1, A2, Bcomb, res_b, bar);
  kfinal<<<dim3(250, BB), 256, 0, stream>>>(acts, SWf, OWf, EWf, SBsum,
      (float*)d_out);
}

// Round 9
// 415.033 us; speedup vs baseline: 1.3202x; 1.0393x over previous
//
#include <hip/hip_runtime.h>
#include <hip/hip_bf16.h>

#define TT 16000
#define BB 4
#define NLAYER 16
#define NBLK 1000    // kchain grid = 250 x 4; ALL co-resident (5 blk/CU x 256 CU = 1280)
#define BARSTR 1088  // u32 per layer-barrier: 34 lines (16 shard + root + 16 release + pad)
#define BARSZ (15 * BARSTR)
#define XCSTR 72    // kchain x-current tile row stride (shorts): 64 + 8
#define XPSTR 72    // kchain halo/acts (aliased) tile row stride
#define ACSTR 72    // kchain acts row stride (same buffer as halo)
#define CDSTR 88    // kchain cond row stride (80 + 8 pad; ks6 tail reads pad/next row, finite & A=0)
#define M3STR 264   // kfinal mid row stride (shorts): 256 + 8 pad
#define ABSTR 72    // kfinal acts-stage row stride (shorts): 64 + 8 pad

#define A1SZ (NLAYER*8*7*512)   // gate-weight A-frags
#define A2SZ (NLAYER*4*2*512)   // res-weight A-frags
#define SWSZ (16*32*512)        // skip-weight A-frags (M=256, K=1024)
#define OWSZ (16*8*512)         // out/end-weight A-frags (M=256, K=256)
#define AUPSZ (20*10*512)       // upsample A-frags (M=320, K=320)
#define BUPSZ (1000*10*512)     // upsample B-frags (K=320, N=16000)

typedef unsigned short ushort_t;
typedef unsigned long long u64_t;
typedef short v8s __attribute__((ext_vector_type(8)));
typedef short v4s __attribute__((ext_vector_type(4)));
typedef float v4f __attribute__((ext_vector_type(4)));

#define MFMA16 __builtin_amdgcn_mfma_f32_16x16x32_bf16

__device__ __forceinline__ float bf2f(ushort_t u) {
  unsigned int x = ((unsigned int)u) << 16;
  float f; __builtin_memcpy(&f, &x, 4); return f;
}
__device__ __forceinline__ ushort_t f2bf(float f) {
  unsigned int x; __builtin_memcpy(&x, &f, 4);
  x += 0x7fffu + ((x >> 16) & 1u);   // RNE
  return (ushort_t)(x >> 16);
}

// ---------------------------------------------------------------------------
// Prep: pack every weight matrix into exact MFMA fragment order (bf16).
// A-frag: elem j of lane l = A[m = mt*16 + (l&15)][k = ks*32 + (l>>4)*8 + j]
// B-frag: elem j of lane l = B[k = ks*32 + (l>>4)*8 + j][n = nt*16 + (l&15)]
// Also: embed gather -> x0, upsample operands Aup/Bup, barrier zeroing.
// (Bup mapping: r0 original — each 64B src line is fully consumed by a
// 16-lane group; writes linear.)
// ---------------------------------------------------------------------------
__global__ __launch_bounds__(256) void kprep(
    const float* __restrict__ feat, const int* __restrict__ fin,
    const float* __restrict__ embed, const float* __restrict__ up_w,
    const float* __restrict__ cond_w, const float* __restrict__ cond_b,
    const float* __restrict__ dil_w, const float* __restrict__ dil_b,
    const float* __restrict__ res_w, const float* __restrict__ skip_w,
    const float* __restrict__ skip_b, const float* __restrict__ out_w,
    const float* __restrict__ end_w,
    ushort_t* __restrict__ A1, ushort_t* __restrict__ A2,
    ushort_t* __restrict__ SWf, ushort_t* __restrict__ OWf,
    ushort_t* __restrict__ EWf, ushort_t* __restrict__ Aup,
    ushort_t* __restrict__ Bup, ushort_t* __restrict__ x0,
    float* __restrict__ Bcomb, float* __restrict__ SBsum,
    unsigned int* __restrict__ bar) {
  int tid = blockIdx.x * 256 + threadIdx.x;
  int np = gridDim.x * 256;
  // zero the kchain grid-barrier state (re-zeroed every iteration/replay)
  for (int idx = tid; idx < BARSZ; idx += np) bar[idx] = 0u;
  // A1: gate GEMM [16 layers][8 Mtiles][7 Ksteps][64 lanes][8]
  // K rows: 0..63 = xc (tap1), 64..127 = xp (tap0), 128..207 = cond, pad=0
  for (int idx = tid; idx < A1SZ; idx += np) {
    int j = idx & 7, lane = (idx >> 3) & 63;
    int r_ = idx >> 9;
    int ks = r_ % 7; int r2 = r_ / 7;
    int mt = r2 & 7; int i = r2 >> 3;
    int m = mt * 16 + (lane & 15);
    int k = ks * 32 + (lane >> 4) * 8 + j;
    float v = 0.f;
    if (k < 64)       v = dil_w[((i * 128 + m) * 64 + k) * 2 + 1];
    else if (k < 128) v = dil_w[((i * 128 + m) * 64 + (k - 64)) * 2 + 0];
    else if (k < 208) v = cond_w[(i * 128 + m) * 80 + (k - 128)];
    A1[idx] = f2bf(v);
  }
  // A2: res GEMM [16][4 Mtiles][2 Ksteps][64][8] (layer 15 zeroed/unused)
  for (int idx = tid; idx < A2SZ; idx += np) {
    int j = idx & 7, lane = (idx >> 3) & 63;
    int r_ = idx >> 9;
    int ks = r_ & 1; int mt = (r_ >> 1) & 3; int i = r_ >> 3;
    int m = mt * 16 + (lane & 15);
    int k = ks * 32 + (lane >> 4) * 8 + j;
    A2[idx] = f2bf(i < 15 ? res_w[(i * 64 + m) * 64 + k] : 0.f);
  }
  // SWf: skip GEMM [16 Mtiles][32 Ksteps][64][8], K = layer*64 + ch
  for (int idx = tid; idx < SWSZ; idx += np) {
    int j = idx & 7, lane = (idx >> 3) & 63;
    int r_ = idx >> 9;
    int ks = r_ & 31; int mt = r_ >> 5;
    int m = mt * 16 + (lane & 15);
    int k = ks * 32 + (lane >> 4) * 8 + j;
    int i = k >> 6, ch = k & 63;
    SWf[idx] = f2bf(skip_w[(i * 256 + m) * 64 + ch]);
  }
  // OWf/EWf: [16 Mtiles][8 Ksteps][64][8]
  for (int idx = tid; idx < OWSZ; idx += np) {
    int j = idx & 7, lane = (idx >> 3) & 63;
    int r_ = idx >> 9;
    int ks = r_ & 7; int mt = r_ >> 3;
    int m = mt * 16 + (lane & 15);
    int k = ks * 32 + (lane >> 4) * 8 + j;
    OWf[idx] = f2bf(out_w[m * 256 + k]);
    EWf[idx] = f2bf(end_w[m * 256 + k]);
  }
  // Aup: [20 Mtiles][10 Ks][64][8]; A[mrow=(b*80+q)][km=(m*80+i)] =
  //   feat[b,i,q-m] (0 if q<m)
  for (int idx = tid; idx < AUPSZ; idx += np) {
    int j = idx & 7, lane = (idx >> 3) & 63;
    int r_ = idx >> 9;
    int ks = r_ % 10; int mt = r_ / 10;
    int mrow = mt * 16 + (lane & 15);
    int km = ks * 32 + (lane >> 4) * 8 + j;
    int b = mrow / 80, q = mrow % 80;
    int m = km / 80, i = km % 80;
    int jj = q - m;
    Aup[idx] = f2bf(jj >= 0 ? feat[(b * 80 + i) * 80 + jj] : 0.f);
  }
  // Bup: [1000 Ntiles][10 Ks][64][8]; B[km][col=(o*200+r)] =
  //   up_w[i, o, 200m + r]  (16 consecutive lanes read 16 consecutive floats)
  for (int idx = tid; idx < BUPSZ; idx += np) {
    int j = idx & 7, lane = (idx >> 3) & 63;
    int r_ = idx >> 9;
    int ks = r_ % 10; int nt = r_ / 10;
    int km = ks * 32 + (lane >> 4) * 8 + j;
    int m = km / 80, i = km % 80;
    int col = nt * 16 + (lane & 15);
    int o = col / 200, r = col % 200;
    Bup[idx] = f2bf(up_w[(size_t)(i * 80 + o) * 800 + m * 200 + r]);
  }
  // embed gather: x0[b][t][ch] bf16
  for (int idx = tid; idx < BB * TT * 64; idx += np) {
    int k = idx & 63;
    int bt = idx >> 6;            // b*TT + t
    x0[idx] = f2bf(embed[fin[bt] * 64 + k]);
  }
  for (int idx = tid; idx < NLAYER * 128; idx += np)
    Bcomb[idx] = dil_b[idx] + cond_b[idx];
  for (int idx = tid; idx < 256; idx += np) {
    float s = 0.f;
    for (int i = 0; i < NLAYER; i++) s += skip_b[i * 256 + idx];
    SBsum[idx] = s;
  }
}

// ---------------------------------------------------------------------------
// Upsample GEMM, MFMA: M=320 (b,q), K=320 (m,i), N=16000 (o*200+r).
// Output cond TRANSPOSED: condT[b][o][t], t = q*200+r. Lanes have
// consecutive r -> consecutive t -> coalesced 32B runs (the old [t][80]
// layout wrote 2B at 160B stride, with partial 64B lines shared across
// XCDs -> write amplification in the non-coherent L2s).
// ---------------------------------------------------------------------------
__global__ __launch_bounds__(256) void kup(
    const ushort_t* __restrict__ Aup, const ushort_t* __restrict__ Bup,
    const float* __restrict__ up_b, ushort_t* __restrict__ condT) {
  int nt0 = blockIdx.x * 4;
  int lane = threadIdx.x & 63;
  int w = threadIdx.x >> 6;
  int tl = lane & 15, quad = lane >> 4;
  v4f acc[5][4];
  #pragma unroll
  for (int mt = 0; mt < 5; mt++)
    #pragma unroll
    for (int nt = 0; nt < 4; nt++) acc[mt][nt] = 0.f;
  #pragma unroll
  for (int ks = 0; ks < 10; ks++) {
    v8s bf[4];
    #pragma unroll
    for (int nt = 0; nt < 4; nt++)
      bf[nt] = *(const v8s*)(Bup + (((size_t)(nt0 + nt) * 10 + ks) * 64 + lane) * 8);
    #pragma unroll
    for (int mt = 0; mt < 5; mt++) {
      v8s a = *(const v8s*)(Aup + (((size_t)(w * 5 + mt) * 10 + ks) * 64 + lane) * 8);
      #pragma unroll
      for (int nt = 0; nt < 4; nt++)
        acc[mt][nt] = MFMA16(a, bf[nt], acc[mt][nt], 0, 0, 0);
    }
  }
  #pragma unroll
  for (int mt = 0; mt < 5; mt++) {
    #pragma unroll
    for (int nt = 0; nt < 4; nt++) {
      int col = (nt0 + nt) * 16 + tl;
      int o = col / 200, r = col % 200;
      float bias = up_b[o];
      #pragma unroll
      for (int rg = 0; rg < 4; rg++) {
        int mrow = (w * 5 + mt) * 16 + quad * 4 + rg;
        int b = mrow / 80, q = mrow % 80;
        condT[((size_t)b * 80 + o) * TT + q * 200 + r] =
            f2bf(acc[mt][nt][rg] + bias);
      }
    }
  }
}

// ---------------------------------------------------------------------------
// Fused 16-layer WaveNet chain. r7 structure with:
//  * Uact ALIASED onto Uhalo (disjoint live ranges; one extra barrier
//    between stage-1 reads and gate writes). LDS 38.5 -> 29.0 KB ->
//    5 blocks/CU (launch_bounds(256,5)); co-residency 1280 >= 1000.
//  * Ucd staged from transposed condT (contiguous 128B per channel row).
//  * acts stored NON-TEMPORAL (written once here, read once by kfinal;
//    keeps the 131MB stream from evicting L2-resident weights).
// Sync: hierarchical barrier + relaxed agent atomics only (r3/r4 lessons).
// ---------------------------------------------------------------------------
__global__ __launch_bounds__(256, 5) void kchain(
    ushort_t* __restrict__ x0g, ushort_t* __restrict__ x1g,
    const ushort_t* __restrict__ condT, ushort_t* __restrict__ actsb,
    const ushort_t* __restrict__ A1, const ushort_t* __restrict__ A2,
    const float* __restrict__ Bcomb, const float* __restrict__ resb,
    unsigned int* __restrict__ bar) {
  __shared__ ushort_t Uxc[64 * XCSTR];       // 9.0 KB current x tile
  __shared__ ushort_t UhAct[64 * XPSTR];     // 9.0 KB halo rows, then acts
  __shared__ ushort_t Ucd[64 * CDSTR + 8];   // 11.0 KB cond tile (+tail pad)
  int b = blockIdx.y;
  int t0 = blockIdx.x * 64;
  int tidx = threadIdx.x;
  int lane = tidx & 63;
  int w = tidx >> 6;
  int tl = lane & 15, quad = lane >> 4;
  int cha = w * 16 + quad * 4;
  const size_t lstr = (size_t)BB * TT * 64;

  // ---- one-time stage: Uxc <- x0, Ucd <- condT (transposing), pad ----
  const ushort_t* xb0 = x0g + ((size_t)b * TT + t0) * 64;
  for (int e = tidx * 8; e < 4096; e += 2048) {
    int t = e >> 6, c = e & 63;
    *(v8s*)&Uxc[t * XCSTR + c] = *(const v8s*)(xb0 + e);
  }
  for (int e = tidx; e < 5120; e += 256) {
    int c = e >> 6, t = e & 63;   // consecutive tidx -> consecutive t: 128B rows
    Ucd[t * CDSTR + c] = condT[((size_t)b * 80 + c) * TT + t0 + t];
  }
  // zero pad cols 80..87 every row + 8 tail shorts (ks6 reads must be finite)
  for (int e2 = tidx; e2 < 520; e2 += 256) {
    if (e2 < 512) Ucd[(e2 >> 3) * CDSTR + 80 + (e2 & 7)] = 0;
    else          Ucd[64 * CDSTR + (e2 - 512)] = 0;
  }
  __syncthreads();

  for (int l = 0; l < NLAYER; l++) {
    int d = 1 << (l & 7);
    int hr = (d < 64) ? d : 64;                 // halo rows staged this layer
    const ushort_t* xing = (l & 1) ? x1g : x0g;
    ushort_t* xoutg = (l & 1) ? x0g : x1g;
    const ushort_t* A1l = A1 + (size_t)l * 8 * 7 * 512;
    const ushort_t* A2l = A2 + (size_t)l * 4 * 2 * 512;
    const float* Bb = Bcomb + l * 128;
    const float* rb = resb + (l < 15 ? l : 0) * 64;
    int last = (l == NLAYER - 1);

    // ---- stage halo into UhAct: ONLY rows t<hr, from left neighbor ----
    for (int e = tidx * 8; e < hr * 64; e += 2048) {
      int t = e >> 6, c = e & 63;
      int tp = t0 + t - d;
      v8s v = (v8s)0;
      if (tp >= 0) {
        const u64_t* p = (const u64_t*)(xing + ((size_t)b * TT + tp) * 64 + c);
        u64_t w0 = __hip_atomic_load(p, __ATOMIC_RELAXED, __HIP_MEMORY_SCOPE_AGENT);
        u64_t w1 = __hip_atomic_load(p + 1, __ATOMIC_RELAXED, __HIP_MEMORY_SCOPE_AGENT);
        __builtin_memcpy(&v, &w0, 8);
        __builtin_memcpy(((char*)&v) + 8, &w1, 8);
      }
      *(v8s*)&UhAct[t * XPSTR + c] = v;
    }
    __syncthreads();

    // ---- stage 1: gate GEMM (xc from Uxc rows t; xp from Uxc[t-d] or
    //      UhAct[t]; cond from Ucd) ----
    v4f acc0[4], acc1[4];
    #pragma unroll
    for (int nt = 0; nt < 4; nt++) { acc0[nt] = 0.f; acc1[nt] = 0.f; }
    #pragma unroll
    for (int ks = 0; ks < 7; ks++) {
      v8s a0 = *(const v8s*)(A1l + (((size_t)w * 7 + ks) * 64 + lane) * 8);
      v8s a1 = *(const v8s*)(A1l + (((size_t)(w + 4) * 7 + ks) * 64 + lane) * 8);
      #pragma unroll
      for (int nt = 0; nt < 4; nt++) {
        int t = nt * 16 + tl;
        const ushort_t* bp;
        if (ks < 2) {
          bp = &Uxc[t * XCSTR + ks * 32 + quad * 8];
        } else if (ks < 4) {
          int toff = t - d;
          bp = (toff >= 0) ? &Uxc[toff * XCSTR + (ks - 2) * 32 + quad * 8]
                           : &UhAct[t * XPSTR + (ks - 2) * 32 + quad * 8];
        } else {
          bp = &Ucd[t * CDSTR + (ks - 4) * 32 + quad * 8];
        }
        v8s bf = *(const v8s*)bp;
        acc0[nt] = MFMA16(a0, bf, acc0[nt], 0, 0, 0);
        acc1[nt] = MFMA16(a1, bf, acc1[nt], 0, 0, 0);
      }
    }
    __syncthreads();   // ALL stage-1 halo reads done before acts overwrite

    // ---- gates: ch = w*16 + quad*4 + r; acts -> UhAct (halo now dead) ----
    float ba[4], bb_[4];
    #pragma unroll
    for (int r = 0; r < 4; r++) { ba[r] = Bb[cha + r]; bb_[r] = Bb[64 + cha + r]; }
    #pragma unroll
    for (int nt = 0; nt < 4; nt++) {
      int t = nt * 16 + tl;
      v4s pk;
      #pragma unroll
      for (int r = 0; r < 4; r++) {
        float ia = acc0[nt][r] + ba[r];
        float ib = acc1[nt][r] + bb_[r];
        float ax = fabsf(ia);
        float e2 = __expf(-2.f * ax);
        float th = __builtin_copysignf((1.f - e2) / (1.f + e2), ia);
        float sg = 1.f / (1.f + __expf(-ib));
        pk[r] = (short)f2bf(th * sg);
      }
      *(v4s*)&UhAct[t * ACSTR + cha] = pk;
    }
    __syncthreads();

    // ---- acts -> global, NON-TEMPORAL (read once by kfinal) ----
    ushort_t* ab = actsb + (size_t)l * lstr + ((size_t)b * TT + t0) * 64;
    for (int e = tidx * 8; e < 4096; e += 2048) {
      int t = e >> 6, c = e & 63;
      v8s v = *(const v8s*)&UhAct[t * ACSTR + c];
      __builtin_nontemporal_store(v, (v8s*)(ab + e));
    }

    if (!last) {
      // ---- stage 2: res GEMM + residual, Uxc updated IN PLACE ----
      v4f acc2[4];
      #pragma unroll
      for (int nt = 0; nt < 4; nt++) {
        v4f z;
        #pragma unroll
        for (int r = 0; r < 4; r++) z[r] = rb[cha + r];
        acc2[nt] = z;
      }
      #pragma unroll
      for (int ks = 0; ks < 2; ks++) {
        v8s a = *(const v8s*)(A2l + (((size_t)w * 2 + ks) * 64 + lane) * 8);
        #pragma unroll
        for (int nt = 0; nt < 4; nt++) {
          v8s bf = *(const v8s*)&UhAct[(nt * 16 + tl) * ACSTR + ks * 32 + quad * 8];
          acc2[nt] = MFMA16(a, bf, acc2[nt], 0, 0, 0);
        }
      }
      #pragma unroll
      for (int nt = 0; nt < 4; nt++) {
        int t = nt * 16 + tl;
        v4s xo = *(const v4s*)&Uxc[t * XCSTR + cha];
        v4s nw;
        #pragma unroll
        for (int r = 0; r < 4; r++)
          nw[r] = (short)f2bf(acc2[nt][r] + bf2f((ushort_t)xo[r]));
        *(v4s*)&Uxc[t * XCSTR + cha] = nw;
      }
      __syncthreads();   // all channels updated before halo snapshot

      // ---- xout halo rows -> LLC via relaxed agent atomics ----
      int dnext = 1 << ((l + 1) & 7);
      int tmin = 64 - (dnext < 64 ? dnext : 64);
      ushort_t* xob = xoutg + ((size_t)b * TT + t0) * 64;
      for (int e = tidx * 8; e < 4096; e += 2048) {
        int t = e >> 6, c = e & 63;
        if (t >= tmin) {
          v8s v = *(const v8s*)&Uxc[t * XCSTR + c];
          u64_t w0, w1;
          __builtin_memcpy(&w0, &v, 8);
          __builtin_memcpy(&w1, ((const char*)&v) + 8, 8);
          u64_t* p = (u64_t*)(xob + e);
          __hip_atomic_store(p, w0, __ATOMIC_RELAXED, __HIP_MEMORY_SCOPE_AGENT);
          __hip_atomic_store(p + 1, w1, __ATOMIC_RELAXED, __HIP_MEMORY_SCOPE_AGENT);
        }
      }

      // ---- hierarchical grid barrier (shard arrive -> root -> release
      //      broadcast; pollers touch ONLY their shard's release line) ----
      __syncthreads();     // drains vmcnt: halo stores globally visible
      if (tidx == 0) {
        unsigned int* L = bar + l * BARSTR;
        int flat = b * 250 + blockIdx.x;           // 0..999
        int shard = flat & 15;                     // 0..7: 63 blks, 8..15: 62
        unsigned int tgt = (shard < 8) ? 62u : 61u;
        unsigned int old = __hip_atomic_fetch_add(L + shard * 32, 1u,
            __ATOMIC_RELAXED, __HIP_MEMORY_SCOPE_AGENT);
        if (old == tgt) {
          unsigned int ro = __hip_atomic_fetch_add(L + 16 * 32, 1u,
              __ATOMIC_RELAXED, __HIP_MEMORY_SCOPE_AGENT);
          if (ro == 15u) {
            #pragma unroll
            for (int s = 0; s < 16; s++)
              __hip_atomic_store(L + (17 + s) * 32, 1u,
                  __ATOMIC_RELAXED, __HIP_MEMORY_SCOPE_AGENT);
          }
        }
        while (__hip_atomic_load(L + (17 + shard) * 32,
            __ATOMIC_RELAXED, __HIP_MEMORY_SCOPE_AGENT) == 0u)
          __builtin_amdgcn_s_sleep(16);
      }
      __syncthreads();
    }
  }
}

// ---------------------------------------------------------------------------
// Final fused MFMA chain — DEPTH-2 register prefetch pipeline (r8, measured
// ~76us): two named reg sets hold tiles l+1/l+2; the tile ds_written at
// layer l was loaded at l-2, so its vmcnt wait is satisfied and a second
// tile stays in flight across the barrier. acts loads NON-TEMPORAL.
// Then +SBsum -> relu -> out (K=256) -> relu -> end -> shift -> f32 store.
// ---------------------------------------------------------------------------
#define KF_COMPUTE(L, BUF)                                                    \
  {                                                                           \
    _Pragma("unroll")                                                         \
    for (int ks2 = 0; ks2 < 2; ks2++) {                                       \
      int ksg = (L) * 2 + ks2;                                                \
      v8s bf[4];                                                              \
      _Pragma("unroll")                                                       \
      for (int nt = 0; nt < 4; nt++)                                          \
        bf[nt] = *(const v8s*)&(BUF)[(nt * 16 + tl) * ABSTR + ks2 * 32 +      \
                                     quad * 8];                               \
      _Pragma("unroll")                                                       \
      for (int mt = 0; mt < 4; mt++) {                                        \
        v8s a = *(const v8s*)(SWf +                                           \
            (((size_t)(w * 4 + mt) * 32 + ksg) * 64 + lane) * 8);             \
        _Pragma("unroll")                                                     \
        for (int nt = 0; nt < 4; nt++)                                        \
          acc[mt][nt] = MFMA16(a, bf[nt], acc[mt][nt], 0, 0, 0);              \
      }                                                                       \
    }                                                                         \
  }

__global__ __launch_bounds__(256) void kfinal(
    const ushort_t* __restrict__ actsb,
    const ushort_t* __restrict__ SWf, const ushort_t* __restrict__ OWf,
    const ushort_t* __restrict__ EWf, const float* __restrict__ SBsum,
    float* __restrict__ dout) {
  __shared__ ushort_t SMEM[64 * M3STR];   // 33 KB; skip-phase: AB dbuf, then M3
  int b = blockIdx.y;
  int t0 = blockIdx.x * 64;
  int tidx = threadIdx.x;
  int lane = tidx & 63;
  int w = tidx >> 6;
  int tl = lane & 15, quad = lane >> 4;

  // ---- skip GEMM, K = 16 layers * 64 ch ----
  v4f acc[4][4];
  #pragma unroll
  for (int mt = 0; mt < 4; mt++) {
    int o = (w * 4 + mt) * 16 + quad * 4;
    #pragma unroll
    for (int nt = 0; nt < 4; nt++) {
      v4f z;
      #pragma unroll
      for (int r = 0; r < 4; r++) z[r] = SBsum[o + r];
      acc[mt][nt] = z;
    }
  }
  const size_t lstr = (size_t)BB * TT * 64;
  int tq = tidx >> 2;               // t-row this thread copies (0..63)
  int pq = (tidx & 3) * 16;         // 16-short chunk within the row
  const ushort_t* a0p = actsb + ((size_t)b * TT + t0) * 64 + tq * 64 + pq;
  {  // stage layer 0 -> buffer 0
    v8s p0 = __builtin_nontemporal_load((const v8s*)(a0p));
    v8s p1 = __builtin_nontemporal_load((const v8s*)(a0p + 8));
    *(v8s*)&SMEM[tq * ABSTR + pq] = p0;
    *(v8s*)&SMEM[tq * ABSTR + pq + 8] = p1;
  }
  // issue prefetches: qa = acts(1), qb = acts(2) — both in flight
  v8s qa0 = __builtin_nontemporal_load((const v8s*)(a0p + 1 * lstr));
  v8s qa1 = __builtin_nontemporal_load((const v8s*)(a0p + 1 * lstr + 8));
  v8s qb0 = __builtin_nontemporal_load((const v8s*)(a0p + 2 * lstr));
  v8s qb1 = __builtin_nontemporal_load((const v8s*)(a0p + 2 * lstr + 8));
  __syncthreads();
  for (int l = 0; l < NLAYER; l += 2) {
    // ---- even layer l: compute from buf0 ----
    KF_COMPUTE(l, SMEM);
    // buf1 <- qa (acts l+1; loaded >=2 layers ago), reissue qa <- acts(l+3)
    *(v8s*)&SMEM[64 * ABSTR + tq * ABSTR + pq] = qa0;
    *(v8s*)&SMEM[64 * ABSTR + tq * ABSTR + pq + 8] = qa1;
    {
      int ln = (l + 3 < NLAYER) ? (l + 3) : (NLAYER - 1);
      qa0 = __builtin_nontemporal_load((const v8s*)(a0p + (size_t)ln * lstr));
      qa1 = __builtin_nontemporal_load((const v8s*)(a0p + (size_t)ln * lstr + 8));
    }
    __syncthreads();
    // ---- odd layer l+1: compute from buf1 ----
    KF_COMPUTE(l + 1, SMEM + 64 * ABSTR);
    // buf0 <- qb (acts l+2; dead at l=14), reissue qb <- acts(l+4)
    *(v8s*)&SMEM[tq * ABSTR + pq] = qb0;
    *(v8s*)&SMEM[tq * ABSTR + pq + 8] = qb1;
    {
      int ln = (l + 4 < NLAYER) ? (l + 4) : (NLAYER - 1);
      qb0 = __builtin_nontemporal_load((const v8s*)(a0p + (size_t)ln * lstr));
      qb1 = __builtin_nontemporal_load((const v8s*)(a0p + (size_t)ln * lstr + 8));
    }
    __syncthreads();
  }
  // ---- SMEM now reused as M3 [t][256+8] ----
  #pragma unroll
  for (int mt = 0; mt < 4; mt++) {
    int o = (w * 4 + mt) * 16 + quad * 4;
    #pragma unroll
    for (int nt = 0; nt < 4; nt++) {
      int t = nt * 16 + tl;
      #pragma unroll
      for (int r = 0; r < 4; r++)
        SMEM[t * M3STR + o + r] = f2bf(fmaxf(acc[mt][nt][r], 0.f));
    }
  }
  __syncthreads();

  // ---- out GEMM, K=256 ----
  v4f acc2[4][4];
  #pragma unroll
  for (int mt = 0; mt < 4; mt++)
    #pragma unroll
    for (int nt = 0; nt < 4; nt++) acc2[mt][nt] = 0.f;
  #pragma unroll
  for (int ks = 0; ks < 8; ks++) {
    v8s bf[4];
    #pragma unroll
    for (int nt = 0; nt < 4; nt++)
      bf[nt] = *(const v8s*)&SMEM[(nt * 16 + tl) * M3STR + ks * 32 + quad * 8];
    #pragma unroll
    for (int mt = 0; mt < 4; mt++) {
      v8s a = *(const v8s*)(OWf + (((size_t)(w * 4 + mt) * 8 + ks) * 64 + lane) * 8);
      #pragma unroll
      for (int nt = 0; nt < 4; nt++)
        acc2[mt][nt] = MFMA16(a, bf[nt], acc2[mt][nt], 0, 0, 0);
    }
  }
  __syncthreads();   // all M3 reads done before overwrite
  #pragma unroll
  for (int mt = 0; mt < 4; mt++) {
    int o = (w * 4 + mt) * 16 + quad * 4;
    #pragma unroll
    for (int nt = 0; nt < 4; nt++) {
      int t = nt * 16 + tl;
      #pragma unroll
      for (int r = 0; r < 4; r++)
        SMEM[t * M3STR + o + r] = f2bf(fmaxf(acc2[mt][nt][r], 0.f));
    }
  }
  __syncthreads();

  // ---- end GEMM, K=256, then shifted store ----
  v4f acc3[4][4];
  #pragma unroll
  for (int mt = 0; mt < 4; mt++)
    #pragma unroll
    for (int nt = 0; nt < 4; nt++) acc3[mt][nt] = 0.f;
  #pragma unroll
  for (int ks = 0; ks < 8; ks++) {
    v8s bf[4];
    #pragma unroll
    for (int nt = 0; nt < 4; nt++)
      bf[nt] = *(const v8s*)&SMEM[(nt * 16 + tl) * M3STR + ks * 32 + quad * 8];
    #pragma unroll
    for (int mt = 0; mt < 4; mt++) {
      v8s a = *(const v8s*)(EWf + (((size_t)(w * 4 + mt) * 8 + ks) * 64 + lane) * 8);
      #pragma unroll
      for (int nt = 0; nt < 4; nt++)
        acc3[mt][nt] = MFMA16(a, bf[nt], acc3[mt][nt], 0, 0, 0);
    }
  }
  #pragma unroll
  for (int mt = 0; mt < 4; mt++) {
    #pragma unroll
    for (int nt = 0; nt < 4; nt++) {
      int tg = t0 + nt * 16 + tl;
      #pragma unroll
      for (int r = 0; r < 4; r++) {
        int o = (w * 4 + mt) * 16 + quad * 4 + r;
        float* ob = dout + ((size_t)b * 256 + o) * TT;
        if (tg == 0) ob[0] = 0.f;
        if (tg + 1 < TT) ob[tg + 1] = acc3[mt][nt][r];
      }
    }
  }
}

// ---------------------------------------------------------------------------
extern "C" void kernel_launch(void* const* d_in, const int* in_sizes, int n_in,
                              void* d_out, int out_size, void* d_ws, size_t ws_size,
                              hipStream_t stream) {
  const float* feat   = (const float*)d_in[0];
  const int*   fin    = (const int*)d_in[1];
  const float* embed  = (const float*)d_in[2];
  const float* up_w   = (const float*)d_in[3];
  const float* up_b   = (const float*)d_in[4];
  const float* cond_w = (const float*)d_in[5];
  const float* cond_b = (const float*)d_in[6];
  const float* dil_w  = (const float*)d_in[7];
  const float* dil_b  = (const float*)d_in[8];
  const float* res_w  = (const float*)d_in[9];
  const float* res_b  = (const float*)d_in[10];
  const float* skip_w = (const float*)d_in[11];
  const float* skip_b = (const float*)d_in[12];
  const float* out_w  = (const float*)d_in[13];
  const float* end_w  = (const float*)d_in[14];

  // Workspace (~175 MB).
  float* ws = (float*)d_ws;
  unsigned int* bar = (unsigned int*)ws;          // barrier state
  size_t off = BARSZ;
  float* Bcomb = ws + off; off += NLAYER * 128;
  float* SBsum = ws + off; off += 256;
  ushort_t* ub = (ushort_t*)(ws + off);
  size_t uo = 0;
  ushort_t* A1    = ub + uo; uo += A1SZ;
  ushort_t* A2    = ub + uo; uo += A2SZ;
  ushort_t* SWf   = ub + uo; uo += SWSZ;
  ushort_t* OWf   = ub + uo; uo += OWSZ;
  ushort_t* EWf   = ub + uo; uo += OWSZ;
  ushort_t* Aup   = ub + uo; uo += AUPSZ;
  ushort_t* Bup   = ub + uo; uo += BUPSZ;
  ushort_t* condT = ub + uo; uo += (size_t)BB * 80 * TT;
  ushort_t* x0    = ub + uo; uo += (size_t)BB * TT * 64;
  ushort_t* x1    = ub + uo; uo += (size_t)BB * TT * 64;
  ushort_t* acts  = ub + uo; uo += (size_t)NLAYER * BB * TT * 64;  // 131 MB

  kprep<<<1024, 256, 0, stream>>>(feat, fin, embed, up_w, cond_w, cond_b,
      dil_w, dil_b, res_w, skip_w, skip_b, out_w, end_w,
      A1, A2, SWf, OWf, EWf, Aup, Bup, x0, Bcomb, SBsum, bar);
  kup<<<250, 256, 0, stream>>>(Aup, Bup, up_b, condT);
  kchain<<<dim3(250, BB), 256, 0, stream>>>(x0, x1, condT, acts,
      A1, A2, Bcomb, res_b, bar);
  kfinal<<<dim3(250, BB), 256, 0, stream>>>(acts, SWf, OWf, EWf, SBsum,
      (float*)d_out);
}

// Round 10
// 398.014 us; speedup vs baseline: 1.3767x; 1.0428x over previous
//
#include <hip/hip_runtime.h>
#include <hip/hip_bf16.h>

#define TT 16000
#define BB 4
#define NLAYER 16
#define NBLK 1000    // kchain grid = 250 x 4; ALL co-resident (4 blk/CU x 256 CU = 1024)
#define BARSTR 1088  // u32 per layer-barrier: 34 lines (16 shard + root + 16 release + pad)
#define BARSZ (15 * BARSTR)
#define XCSTR 72    // kchain x-current tile row stride (shorts): 64 + 8
#define XPSTR 72    // kchain halo tile row stride
#define ACSTR 72    // kchain acts row stride
#define CDSTR 88    // kchain cond row stride (80 + 8 pad; ks6 tail reads pad/next row, finite & A=0)
#define M3STR 264   // kfinal mid row stride (shorts): 256 + 8 pad
#define ABSTR 72    // kfinal acts-stage row stride (shorts): 64 + 8 pad

#define A1SZ (NLAYER*8*7*512)   // gate-weight A-frags
#define A2SZ (NLAYER*4*2*512)   // res-weight A-frags
#define SWSZ (16*32*512)        // skip-weight A-frags (M=256, K=1024)
#define OWSZ (16*8*512)         // out/end-weight A-frags (M=256, K=256)
#define AUPSZ (20*10*512)       // upsample A-frags (M=320, K=320)
#define BUPSZ (1000*10*512)     // upsample B-frags (K=320, N=16000)

typedef unsigned short ushort_t;
typedef unsigned long long u64_t;
typedef short v8s __attribute__((ext_vector_type(8)));
typedef short v4s __attribute__((ext_vector_type(4)));
typedef float v4f __attribute__((ext_vector_type(4)));

#define MFMA16 __builtin_amdgcn_mfma_f32_16x16x32_bf16

__device__ __forceinline__ float bf2f(ushort_t u) {
  unsigned int x = ((unsigned int)u) << 16;
  float f; __builtin_memcpy(&f, &x, 4); return f;
}
__device__ __forceinline__ ushort_t f2bf(float f) {
  unsigned int x; __builtin_memcpy(&x, &f, 4);
  x += 0x7fffu + ((x >> 16) & 1u);   // RNE
  return (ushort_t)(x >> 16);
}

// ---------------------------------------------------------------------------
// Prep: pack every weight matrix into exact MFMA fragment order (bf16).
// A-frag: elem j of lane l = A[m = mt*16 + (l&15)][k = ks*32 + (l>>4)*8 + j]
// B-frag: elem j of lane l = B[k = ks*32 + (l>>4)*8 + j][n = nt*16 + (l&15)]
// Also: embed gather -> x0, upsample operands Aup/Bup, barrier zeroing.
// ---------------------------------------------------------------------------
__global__ __launch_bounds__(256) void kprep(
    const float* __restrict__ feat, const int* __restrict__ fin,
    const float* __restrict__ embed, const float* __restrict__ up_w,
    const float* __restrict__ cond_w, const float* __restrict__ cond_b,
    const float* __restrict__ dil_w, const float* __restrict__ dil_b,
    const float* __restrict__ res_w, const float* __restrict__ skip_w,
    const float* __restrict__ skip_b, const float* __restrict__ out_w,
    const float* __restrict__ end_w,
    ushort_t* __restrict__ A1, ushort_t* __restrict__ A2,
    ushort_t* __restrict__ SWf, ushort_t* __restrict__ OWf,
    ushort_t* __restrict__ EWf, ushort_t* __restrict__ Aup,
    ushort_t* __restrict__ Bup, ushort_t* __restrict__ x0,
    float* __restrict__ Bcomb, float* __restrict__ SBsum,
    unsigned int* __restrict__ bar) {
  int tid = blockIdx.x * 256 + threadIdx.x;
  int np = gridDim.x * 256;
  // zero the kchain grid-barrier state (re-zeroed every iteration/replay)
  for (int idx = tid; idx < BARSZ; idx += np) bar[idx] = 0u;
  // A1: gate GEMM [16 layers][8 Mtiles][7 Ksteps][64 lanes][8]
  // K rows: 0..63 = xc (tap1), 64..127 = xp (tap0), 128..207 = cond, pad=0
  for (int idx = tid; idx < A1SZ; idx += np) {
    int j = idx & 7, lane = (idx >> 3) & 63;
    int r_ = idx >> 9;
    int ks = r_ % 7; int r2 = r_ / 7;
    int mt = r2 & 7; int i = r2 >> 3;
    int m = mt * 16 + (lane & 15);
    int k = ks * 32 + (lane >> 4) * 8 + j;
    float v = 0.f;
    if (k < 64)       v = dil_w[((i * 128 + m) * 64 + k) * 2 + 1];
    else if (k < 128) v = dil_w[((i * 128 + m) * 64 + (k - 64)) * 2 + 0];
    else if (k < 208) v = cond_w[(i * 128 + m) * 80 + (k - 128)];
    A1[idx] = f2bf(v);
  }
  // A2: res GEMM [16][4 Mtiles][2 Ksteps][64][8] (layer 15 zeroed/unused)
  for (int idx = tid; idx < A2SZ; idx += np) {
    int j = idx & 7, lane = (idx >> 3) & 63;
    int r_ = idx >> 9;
    int ks = r_ & 1; int mt = (r_ >> 1) & 3; int i = r_ >> 3;
    int m = mt * 16 + (lane & 15);
    int k = ks * 32 + (lane >> 4) * 8 + j;
    A2[idx] = f2bf(i < 15 ? res_w[(i * 64 + m) * 64 + k] : 0.f);
  }
  // SWf: skip GEMM [16 Mtiles][32 Ksteps][64][8], K = layer*64 + ch
  for (int idx = tid; idx < SWSZ; idx += np) {
    int j = idx & 7, lane = (idx >> 3) & 63;
    int r_ = idx >> 9;
    int ks = r_ & 31; int mt = r_ >> 5;
    int m = mt * 16 + (lane & 15);
    int k = ks * 32 + (lane >> 4) * 8 + j;
    int i = k >> 6, ch = k & 63;
    SWf[idx] = f2bf(skip_w[(i * 256 + m) * 64 + ch]);
  }
  // OWf/EWf: [16 Mtiles][8 Ksteps][64][8]
  for (int idx = tid; idx < OWSZ; idx += np) {
    int j = idx & 7, lane = (idx >> 3) & 63;
    int r_ = idx >> 9;
    int ks = r_ & 7; int mt = r_ >> 3;
    int m = mt * 16 + (lane & 15);
    int k = ks * 32 + (lane >> 4) * 8 + j;
    OWf[idx] = f2bf(out_w[m * 256 + k]);
    EWf[idx] = f2bf(end_w[m * 256 + k]);
  }
  // Aup: [20 Mtiles][10 Ks][64][8]; A[mrow=(b*80+q)][km=(m*80+i)] =
  //   feat[b,i,q-m] (0 if q<m)
  for (int idx = tid; idx < AUPSZ; idx += np) {
    int j = idx & 7, lane = (idx >> 3) & 63;
    int r_ = idx >> 9;
    int ks = r_ % 10; int mt = r_ / 10;
    int mrow = mt * 16 + (lane & 15);
    int km = ks * 32 + (lane >> 4) * 8 + j;
    int b = mrow / 80, q = mrow % 80;
    int m = km / 80, i = km % 80;
    int jj = q - m;
    Aup[idx] = f2bf(jj >= 0 ? feat[(b * 80 + i) * 80 + jj] : 0.f);
  }
  // Bup: [1000 Ntiles][10 Ks][64][8]; B[km][col=(o*200+r)] =
  //   up_w[i, o, 200m + r]  (16 consecutive lanes read 16 consecutive floats)
  for (int idx = tid; idx < BUPSZ; idx += np) {
    int j = idx & 7, lane = (idx >> 3) & 63;
    int r_ = idx >> 9;
    int ks = r_ % 10; int nt = r_ / 10;
    int km = ks * 32 + (lane >> 4) * 8 + j;
    int m = km / 80, i = km % 80;
    int col = nt * 16 + (lane & 15);
    int o = col / 200, r = col % 200;
    Bup[idx] = f2bf(up_w[(size_t)(i * 80 + o) * 800 + m * 200 + r]);
  }
  // embed gather: x0[b][t][ch] bf16
  for (int idx = tid; idx < BB * TT * 64; idx += np) {
    int k = idx & 63;
    int bt = idx >> 6;            // b*TT + t
    x0[idx] = f2bf(embed[fin[bt] * 64 + k]);
  }
  for (int idx = tid; idx < NLAYER * 128; idx += np)
    Bcomb[idx] = dil_b[idx] + cond_b[idx];
  for (int idx = tid; idx < 256; idx += np) {
    float s = 0.f;
    for (int i = 0; i < NLAYER; i++) s += skip_b[i * 256 + idx];
    SBsum[idx] = s;
  }
}

// ---------------------------------------------------------------------------
// Upsample GEMM, MFMA: M=320 (b,q), K=320 (m,i), N=16000 (o*200+r).
// Output cond TRANSPOSED: condT[b][o][t], t = q*200+r (r9-proven: coalesced
// 32B runs vs the old [t][80] layout's 2B-at-160B-stride scatter).
// ---------------------------------------------------------------------------
__global__ __launch_bounds__(256) void kup(
    const ushort_t* __restrict__ Aup, const ushort_t* __restrict__ Bup,
    const float* __restrict__ up_b, ushort_t* __restrict__ condT) {
  int nt0 = blockIdx.x * 4;
  int lane = threadIdx.x & 63;
  int w = threadIdx.x >> 6;
  int tl = lane & 15, quad = lane >> 4;
  v4f acc[5][4];
  #pragma unroll
  for (int mt = 0; mt < 5; mt++)
    #pragma unroll
    for (int nt = 0; nt < 4; nt++) acc[mt][nt] = 0.f;
  #pragma unroll
  for (int ks = 0; ks < 10; ks++) {
    v8s bf[4];
    #pragma unroll
    for (int nt = 0; nt < 4; nt++)
      bf[nt] = *(const v8s*)(Bup + (((size_t)(nt0 + nt) * 10 + ks) * 64 + lane) * 8);
    #pragma unroll
    for (int mt = 0; mt < 5; mt++) {
      v8s a = *(const v8s*)(Aup + (((size_t)(w * 5 + mt) * 10 + ks) * 64 + lane) * 8);
      #pragma unroll
      for (int nt = 0; nt < 4; nt++)
        acc[mt][nt] = MFMA16(a, bf[nt], acc[mt][nt], 0, 0, 0);
    }
  }
  #pragma unroll
  for (int mt = 0; mt < 5; mt++) {
    #pragma unroll
    for (int nt = 0; nt < 4; nt++) {
      int col = (nt0 + nt) * 16 + tl;
      int o = col / 200, r = col % 200;
      float bias = up_b[o];
      #pragma unroll
      for (int rg = 0; rg < 4; rg++) {
        int mrow = (w * 5 + mt) * 16 + quad * 4 + rg;
        int b = mrow / 80, q = mrow % 80;
        condT[((size_t)b * 80 + o) * TT + q * 200 + r] =
            f2bf(acc[mt][nt][rg] + bias);
      }
    }
  }
}

// ---------------------------------------------------------------------------
// Fused 16-layer WaveNet chain — r8 structure (196 us measured): separate
// Uhalo/Uact buffers (no alias barrier — occupancy is GRID-capped at ~4
// blk/CU so smaller LDS buys nothing), plain acts stores (NT pushed the
// LLC-resident acts stream to HBM — r9 regression). Only r9 keeper: Ucd
// staged from transposed condT (contiguous 128B per channel row).
// Sync: hierarchical barrier + relaxed agent atomics only (r3/r4 lessons).
// ---------------------------------------------------------------------------
__global__ __launch_bounds__(256, 4) void kchain(
    ushort_t* __restrict__ x0g, ushort_t* __restrict__ x1g,
    const ushort_t* __restrict__ condT, ushort_t* __restrict__ actsb,
    const ushort_t* __restrict__ A1, const ushort_t* __restrict__ A2,
    const float* __restrict__ Bcomb, const float* __restrict__ resb,
    unsigned int* __restrict__ bar) {
  __shared__ ushort_t Uxc[64 * XCSTR];       // 9.0 KB current x tile
  __shared__ ushort_t Uhalo[64 * XPSTR];     // 9.0 KB halo rows (t < d)
  __shared__ ushort_t Uact[64 * ACSTR];      // 9.0 KB gate acts
  __shared__ ushort_t Ucd[64 * CDSTR + 8];   // 11.0 KB cond tile (+tail pad)
  int b = blockIdx.y;
  int t0 = blockIdx.x * 64;
  int tidx = threadIdx.x;
  int lane = tidx & 63;
  int w = tidx >> 6;
  int tl = lane & 15, quad = lane >> 4;
  int cha = w * 16 + quad * 4;
  const size_t lstr = (size_t)BB * TT * 64;

  // ---- one-time stage: Uxc <- x0, Ucd <- condT (transposing), pad ----
  const ushort_t* xb0 = x0g + ((size_t)b * TT + t0) * 64;
  for (int e = tidx * 8; e < 4096; e += 2048) {
    int t = e >> 6, c = e & 63;
    *(v8s*)&Uxc[t * XCSTR + c] = *(const v8s*)(xb0 + e);
  }
  for (int e = tidx; e < 5120; e += 256) {
    int c = e >> 6, t = e & 63;   // consecutive tidx -> consecutive t: 128B rows
    Ucd[t * CDSTR + c] = condT[((size_t)b * 80 + c) * TT + t0 + t];
  }
  // zero pad cols 80..87 every row + 8 tail shorts (ks6 reads must be finite)
  for (int e2 = tidx; e2 < 520; e2 += 256) {
    if (e2 < 512) Ucd[(e2 >> 3) * CDSTR + 80 + (e2 & 7)] = 0;
    else          Ucd[64 * CDSTR + (e2 - 512)] = 0;
  }
  __syncthreads();

  for (int l = 0; l < NLAYER; l++) {
    int d = 1 << (l & 7);
    int hr = (d < 64) ? d : 64;                 // halo rows staged this layer
    const ushort_t* xing = (l & 1) ? x1g : x0g;
    ushort_t* xoutg = (l & 1) ? x0g : x1g;
    const ushort_t* A1l = A1 + (size_t)l * 8 * 7 * 512;
    const ushort_t* A2l = A2 + (size_t)l * 4 * 2 * 512;
    const float* Bb = Bcomb + l * 128;
    const float* rb = resb + (l < 15 ? l : 0) * 64;
    int last = (l == NLAYER - 1);

    // ---- stage Uhalo: ONLY rows t<hr, from left neighbor (LLC atomics) ----
    for (int e = tidx * 8; e < hr * 64; e += 2048) {
      int t = e >> 6, c = e & 63;
      int tp = t0 + t - d;
      v8s v = (v8s)0;
      if (tp >= 0) {
        const u64_t* p = (const u64_t*)(xing + ((size_t)b * TT + tp) * 64 + c);
        u64_t w0 = __hip_atomic_load(p, __ATOMIC_RELAXED, __HIP_MEMORY_SCOPE_AGENT);
        u64_t w1 = __hip_atomic_load(p + 1, __ATOMIC_RELAXED, __HIP_MEMORY_SCOPE_AGENT);
        __builtin_memcpy(&v, &w0, 8);
        __builtin_memcpy(((char*)&v) + 8, &w1, 8);
      }
      *(v8s*)&Uhalo[t * XPSTR + c] = v;
    }
    __syncthreads();

    // ---- stage 1: gate GEMM (xc from Uxc rows t; xp from Uxc[t-d] or
    //      Uhalo[t]; cond from Ucd) ----
    v4f acc0[4], acc1[4];
    #pragma unroll
    for (int nt = 0; nt < 4; nt++) { acc0[nt] = 0.f; acc1[nt] = 0.f; }
    #pragma unroll
    for (int ks = 0; ks < 7; ks++) {
      v8s a0 = *(const v8s*)(A1l + (((size_t)w * 7 + ks) * 64 + lane) * 8);
      v8s a1 = *(const v8s*)(A1l + (((size_t)(w + 4) * 7 + ks) * 64 + lane) * 8);
      #pragma unroll
      for (int nt = 0; nt < 4; nt++) {
        int t = nt * 16 + tl;
        const ushort_t* bp;
        if (ks < 2) {
          bp = &Uxc[t * XCSTR + ks * 32 + quad * 8];
        } else if (ks < 4) {
          int toff = t - d;
          bp = (toff >= 0) ? &Uxc[toff * XCSTR + (ks - 2) * 32 + quad * 8]
                           : &Uhalo[t * XPSTR + (ks - 2) * 32 + quad * 8];
        } else {
          bp = &Ucd[t * CDSTR + (ks - 4) * 32 + quad * 8];
        }
        v8s bf = *(const v8s*)bp;
        acc0[nt] = MFMA16(a0, bf, acc0[nt], 0, 0, 0);
        acc1[nt] = MFMA16(a1, bf, acc1[nt], 0, 0, 0);
      }
    }

    // ---- gates: ch = w*16 + quad*4 + r (pair ch, ch+64 lane-local) ----
    float ba[4], bb_[4];
    #pragma unroll
    for (int r = 0; r < 4; r++) { ba[r] = Bb[cha + r]; bb_[r] = Bb[64 + cha + r]; }
    #pragma unroll
    for (int nt = 0; nt < 4; nt++) {
      int t = nt * 16 + tl;
      v4s pk;
      #pragma unroll
      for (int r = 0; r < 4; r++) {
        float ia = acc0[nt][r] + ba[r];
        float ib = acc1[nt][r] + bb_[r];
        float ax = fabsf(ia);
        float e2 = __expf(-2.f * ax);
        float th = __builtin_copysignf((1.f - e2) / (1.f + e2), ia);
        float sg = 1.f / (1.f + __expf(-ib));
        pk[r] = (short)f2bf(th * sg);
      }
      *(v4s*)&Uact[t * ACSTR + cha] = pk;
    }
    __syncthreads();

    // ---- acts -> global (kfinal's deferred skip GEMM reads these) ----
    ushort_t* ab = actsb + (size_t)l * lstr + ((size_t)b * TT + t0) * 64;
    for (int e = tidx * 8; e < 4096; e += 2048) {
      int t = e >> 6, c = e & 63;
      *(v8s*)(ab + e) = *(const v8s*)&Uact[t * ACSTR + c];
    }

    if (!last) {
      // ---- stage 2: res GEMM + residual, Uxc updated IN PLACE ----
      v4f acc2[4];
      #pragma unroll
      for (int nt = 0; nt < 4; nt++) {
        v4f z;
        #pragma unroll
        for (int r = 0; r < 4; r++) z[r] = rb[cha + r];
        acc2[nt] = z;
      }
      #pragma unroll
      for (int ks = 0; ks < 2; ks++) {
        v8s a = *(const v8s*)(A2l + (((size_t)w * 2 + ks) * 64 + lane) * 8);
        #pragma unroll
        for (int nt = 0; nt < 4; nt++) {
          v8s bf = *(const v8s*)&Uact[(nt * 16 + tl) * ACSTR + ks * 32 + quad * 8];
          acc2[nt] = MFMA16(a, bf, acc2[nt], 0, 0, 0);
        }
      }
      #pragma unroll
      for (int nt = 0; nt < 4; nt++) {
        int t = nt * 16 + tl;
        v4s xo = *(const v4s*)&Uxc[t * XCSTR + cha];
        v4s nw;
        #pragma unroll
        for (int r = 0; r < 4; r++)
          nw[r] = (short)f2bf(acc2[nt][r] + bf2f((ushort_t)xo[r]));
        *(v4s*)&Uxc[t * XCSTR + cha] = nw;
      }
      __syncthreads();   // all channels updated before halo snapshot

      // ---- xout halo rows -> LLC via relaxed agent atomics ----
      int dnext = 1 << ((l + 1) & 7);
      int tmin = 64 - (dnext < 64 ? dnext : 64);
      ushort_t* xob = xoutg + ((size_t)b * TT + t0) * 64;
      for (int e = tidx * 8; e < 4096; e += 2048) {
        int t = e >> 6, c = e & 63;
        if (t >= tmin) {
          v8s v = *(const v8s*)&Uxc[t * XCSTR + c];
          u64_t w0, w1;
          __builtin_memcpy(&w0, &v, 8);
          __builtin_memcpy(&w1, ((const char*)&v) + 8, 8);
          u64_t* p = (u64_t*)(xob + e);
          __hip_atomic_store(p, w0, __ATOMIC_RELAXED, __HIP_MEMORY_SCOPE_AGENT);
          __hip_atomic_store(p + 1, w1, __ATOMIC_RELAXED, __HIP_MEMORY_SCOPE_AGENT);
        }
      }

      // ---- hierarchical grid barrier (shard arrive -> root -> release
      //      broadcast; pollers touch ONLY their shard's release line) ----
      __syncthreads();     // drains vmcnt: halo stores globally visible
      if (tidx == 0) {
        unsigned int* L = bar + l * BARSTR;
        int flat = b * 250 + blockIdx.x;           // 0..999
        int shard = flat & 15;                     // 0..7: 63 blks, 8..15: 62
        unsigned int tgt = (shard < 8) ? 62u : 61u;
        unsigned int old = __hip_atomic_fetch_add(L + shard * 32, 1u,
            __ATOMIC_RELAXED, __HIP_MEMORY_SCOPE_AGENT);
        if (old == tgt) {
          unsigned int ro = __hip_atomic_fetch_add(L + 16 * 32, 1u,
              __ATOMIC_RELAXED, __HIP_MEMORY_SCOPE_AGENT);
          if (ro == 15u) {
            #pragma unroll
            for (int s = 0; s < 16; s++)
              __hip_atomic_store(L + (17 + s) * 32, 1u,
                  __ATOMIC_RELAXED, __HIP_MEMORY_SCOPE_AGENT);
          }
        }
        while (__hip_atomic_load(L + (17 + shard) * 32,
            __ATOMIC_RELAXED, __HIP_MEMORY_SCOPE_AGENT) == 0u)
          __builtin_amdgcn_s_sleep(16);
      }
      __syncthreads();
    }
  }
}

// ---------------------------------------------------------------------------
// Final fused MFMA chain — DEPTH-2 register prefetch pipeline (r8, measured
// ~76us): two named reg sets hold tiles l+1/l+2; the tile ds_written at
// layer l was loaded at l-2, so its vmcnt wait is satisfied and a second
// tile stays in flight across the barrier. Plain loads (acts is
// LLC-resident; NT hints regressed in r9).
// Then +SBsum -> relu -> out (K=256) -> relu -> end -> shift -> f32 store.
// ---------------------------------------------------------------------------
#define KF_COMPUTE(L, BUF)                                                    \
  {                                                                           \
    _Pragma("unroll")                                                         \
    for (int ks2 = 0; ks2 < 2; ks2++) {                                       \
      int ksg = (L) * 2 + ks2;                                                \
      v8s bf[4];                                                              \
      _Pragma("unroll")                                                       \
      for (int nt = 0; nt < 4; nt++)                                          \
        bf[nt] = *(const v8s*)&(BUF)[(nt * 16 + tl) * ABSTR + ks2 * 32 +      \
                                     quad * 8];                               \
      _Pragma("unroll")                                                       \
      for (int mt = 0; mt < 4; mt++) {                                        \
        v8s a = *(const v8s*)(SWf +                                           \
            (((size_t)(w * 4 + mt) * 32 + ksg) * 64 + lane) * 8);             \
        _Pragma("unroll")                                                     \
        for (int nt = 0; nt < 4; nt++)                                        \
          acc[mt][nt] = MFMA16(a, bf[nt], acc[mt][nt], 0, 0, 0);              \
      }                                                                       \
    }                                                                         \
  }

__global__ __launch_bounds__(256) void kfinal(
    const ushort_t* __restrict__ actsb,
    const ushort_t* __restrict__ SWf, const ushort_t* __restrict__ OWf,
    const ushort_t* __restrict__ EWf, const float* __restrict__ SBsum,
    float* __restrict__ dout) {
  __shared__ ushort_t SMEM[64 * M3STR];   // 33 KB; skip-phase: AB dbuf, then M3
  int b = blockIdx.y;
  int t0 = blockIdx.x * 64;
  int tidx = threadIdx.x;
  int lane = tidx & 63;
  int w = tidx >> 6;
  int tl = lane & 15, quad = lane >> 4;

  // ---- skip GEMM, K = 16 layers * 64 ch ----
  v4f acc[4][4];
  #pragma unroll
  for (int mt = 0; mt < 4; mt++) {
    int o = (w * 4 + mt) * 16 + quad * 4;
    #pragma unroll
    for (int nt = 0; nt < 4; nt++) {
      v4f z;
      #pragma unroll
      for (int r = 0; r < 4; r++) z[r] = SBsum[o + r];
      acc[mt][nt] = z;
    }
  }
  const size_t lstr = (size_t)BB * TT * 64;
  int tq = tidx >> 2;               // t-row this thread copies (0..63)
  int pq = (tidx & 3) * 16;         // 16-short chunk within the row
  const ushort_t* a0p = actsb + ((size_t)b * TT + t0) * 64 + tq * 64 + pq;
  {  // stage layer 0 -> buffer 0
    v8s p0 = *(const v8s*)(a0p);
    v8s p1 = *(const v8s*)(a0p + 8);
    *(v8s*)&SMEM[tq * ABSTR + pq] = p0;
    *(v8s*)&SMEM[tq * ABSTR + pq + 8] = p1;
  }
  // issue prefetches: qa = acts(1), qb = acts(2) — both in flight
  v8s qa0 = *(const v8s*)(a0p + 1 * lstr);
  v8s qa1 = *(const v8s*)(a0p + 1 * lstr + 8);
  v8s qb0 = *(const v8s*)(a0p + 2 * lstr);
  v8s qb1 = *(const v8s*)(a0p + 2 * lstr + 8);
  __syncthreads();
  for (int l = 0; l < NLAYER; l += 2) {
    // ---- even layer l: compute from buf0 ----
    KF_COMPUTE(l, SMEM);
    // buf1 <- qa (acts l+1; loaded >=2 layers ago), reissue qa <- acts(l+3)
    *(v8s*)&SMEM[64 * ABSTR + tq * ABSTR + pq] = qa0;
    *(v8s*)&SMEM[64 * ABSTR + tq * ABSTR + pq + 8] = qa1;
    {
      int ln = (l + 3 < NLAYER) ? (l + 3) : (NLAYER - 1);
      qa0 = *(const v8s*)(a0p + (size_t)ln * lstr);
      qa1 = *(const v8s*)(a0p + (size_t)ln * lstr + 8);
    }
    __syncthreads();
    // ---- odd layer l+1: compute from buf1 ----
    KF_COMPUTE(l + 1, SMEM + 64 * ABSTR);
    // buf0 <- qb (acts l+2; dead at l=14), reissue qb <- acts(l+4)
    *(v8s*)&SMEM[tq * ABSTR + pq] = qb0;
    *(v8s*)&SMEM[tq * ABSTR + pq + 8] = qb1;
    {
      int ln = (l + 4 < NLAYER) ? (l + 4) : (NLAYER - 1);
      qb0 = *(const v8s*)(a0p + (size_t)ln * lstr);
      qb1 = *(const v8s*)(a0p + (size_t)ln * lstr + 8);
    }
    __syncthreads();
  }
  // ---- SMEM now reused as M3 [t][256+8] ----
  #pragma unroll
  for (int mt = 0; mt < 4; mt++) {
    int o = (w * 4 + mt) * 16 + quad * 4;
    #pragma unroll
    for (int nt = 0; nt < 4; nt++) {
      int t = nt * 16 + tl;
      #pragma unroll
      for (int r = 0; r < 4; r++)
        SMEM[t * M3STR + o + r] = f2bf(fmaxf(acc[mt][nt][r], 0.f));
    }
  }
  __syncthreads();

  // ---- out GEMM, K=256 ----
  v4f acc2[4][4];
  #pragma unroll
  for (int mt = 0; mt < 4; mt++)
    #pragma unroll
    for (int nt = 0; nt < 4; nt++) acc2[mt][nt] = 0.f;
  #pragma unroll
  for (int ks = 0; ks < 8; ks++) {
    v8s bf[4];
    #pragma unroll
    for (int nt = 0; nt < 4; nt++)
      bf[nt] = *(const v8s*)&SMEM[(nt * 16 + tl) * M3STR + ks * 32 + quad * 8];
    #pragma unroll
    for (int mt = 0; mt < 4; mt++) {
      v8s a = *(const v8s*)(OWf + (((size_t)(w * 4 + mt) * 8 + ks) * 64 + lane) * 8);
      #pragma unroll
      for (int nt = 0; nt < 4; nt++)
        acc2[mt][nt] = MFMA16(a, bf[nt], acc2[mt][nt], 0, 0, 0);
    }
  }
  __syncthreads();   // all M3 reads done before overwrite
  #pragma unroll
  for (int mt = 0; mt < 4; mt++) {
    int o = (w * 4 + mt) * 16 + quad * 4;
    #pragma unroll
    for (int nt = 0; nt < 4; nt++) {
      int t = nt * 16 + tl;
      #pragma unroll
      for (int r = 0; r < 4; r++)
        SMEM[t * M3STR + o + r] = f2bf(fmaxf(acc2[mt][nt][r], 0.f));
    }
  }
  __syncthreads();

  // ---- end GEMM, K=256, then shifted store ----
  v4f acc3[4][4];
  #pragma unroll
  for (int mt = 0; mt < 4; mt++)
    #pragma unroll
    for (int nt = 0; nt < 4; nt++) acc3[mt][nt] = 0.f;
  #pragma unroll
  for (int ks = 0; ks < 8; ks++) {
    v8s bf[4];
    #pragma unroll
    for (int nt = 0; nt < 4; nt++)
      bf[nt] = *(const v8s*)&SMEM[(nt * 16 + tl) * M3STR + ks * 32 + quad * 8];
    #pragma unroll
    for (int mt = 0; mt < 4; mt++) {
      v8s a = *(const v8s*)(EWf + (((size_t)(w * 4 + mt) * 8 + ks) * 64 + lane) * 8);
      #pragma unroll
      for (int nt = 0; nt < 4; nt++)
        acc3[mt][nt] = MFMA16(a, bf[nt], acc3[mt][nt], 0, 0, 0);
    }
  }
  #pragma unroll
  for (int mt = 0; mt < 4; mt++) {
    #pragma unroll
    for (int nt = 0; nt < 4; nt++) {
      int tg = t0 + nt * 16 + tl;
      #pragma unroll
      for (int r = 0; r < 4; r++) {
        int o = (w * 4 + mt) * 16 + quad * 4 + r;
        float* ob = dout + ((size_t)b * 256 + o) * TT;
        if (tg == 0) ob[0] = 0.f;
        if (tg + 1 < TT) ob[tg + 1] = acc3[mt][nt][r];
      }
    }
  }
}

// ---------------------------------------------------------------------------
extern "C" void kernel_launch(void* const* d_in, const int* in_sizes, int n_in,
                              void* d_out, int out_size, void* d_ws, size_t ws_size,
                              hipStream_t stream) {
  const float* feat   = (const float*)d_in[0];
  const int*   fin    = (const int*)d_in[1];
  const float* embed  = (const float*)d_in[2];
  const float* up_w   = (const float*)d_in[3];
  const float* up_b   = (const float*)d_in[4];
  const float* cond_w = (const float*)d_in[5];
  const float* cond_b = (const float*)d_in[6];
  const float* dil_w  = (const float*)d_in[7];
  const float* dil_b  = (const float*)d_in[8];
  const float* res_w  = (const float*)d_in[9];
  const float* res_b  = (const float*)d_in[10];
  const float* skip_w = (const float*)d_in[11];
  const float* skip_b = (const float*)d_in[12];
  const float* out_w  = (const float*)d_in[13];
  const float* end_w  = (const float*)d_in[14];

  // Workspace (~175 MB).
  float* ws = (float*)d_ws;
  unsigned int* bar = (unsigned int*)ws;          // barrier state
  size_t off = BARSZ;
  float* Bcomb = ws + off; off += NLAYER * 128;
  float* SBsum = ws + off; off += 256;
  ushort_t* ub = (ushort_t*)(ws + off);
  size_t uo = 0;
  ushort_t* A1    = ub + uo; uo += A1SZ;
  ushort_t* A2    = ub + uo; uo += A2SZ;
  ushort_t* SWf   = ub + uo; uo += SWSZ;
  ushort_t* OWf   = ub + uo; uo += OWSZ;
  ushort_t* EWf   = ub + uo; uo += OWSZ;
  ushort_t* Aup   = ub + uo; uo += AUPSZ;
  ushort_t* Bup   = ub + uo; uo += BUPSZ;
  ushort_t* condT = ub + uo; uo += (size_t)BB * 80 * TT;
  ushort_t* x0    = ub + uo; uo += (size_t)BB * TT * 64;
  ushort_t* x1    = ub + uo; uo += (size_t)BB * TT * 64;
  ushort_t* acts  = ub + uo; uo += (size_t)NLAYER * BB * TT * 64;  // 131 MB

  kprep<<<1024, 256, 0, stream>>>(feat, fin, embed, up_w, cond_w, cond_b,
      dil_w, dil_b, res_w, skip_w, skip_b, out_w, end_w,
      A1, A2, SWf, OWf, EWf, Aup, Bup, x0, Bcomb, SBsum, bar);
  kup<<<250, 256, 0, stream>>>(Aup, Bup, up_b, condT);
  kchain<<<dim3(250, BB), 256, 0, stream>>>(x0, x1, condT, acts,
      A1, A2, Bcomb, res_b, bar);
  kfinal<<<dim3(250, BB), 256, 0, stream>>>(acts, SWf, OWf, EWf, SBsum,
      (float*)d_out);
}

// Round 11
// 375.481 us; speedup vs baseline: 1.4593x; 1.0600x over previous
//
#include <hip/hip_runtime.h>
#include <hip/hip_bf16.h>

#define TT 16000
#define BB 4
#define NLAYER 16
#define NBLK 1000    // kchain grid = 250 x 4; ALL co-resident (4 blk/CU x 256 CU = 1024)
#define BARSTR 1088  // u32 per layer-barrier: 34 lines (16 shard + root + 16 release + pad)
#define BARSZ (15 * BARSTR)
#define XCSTR 72    // kchain x-current tile row stride (shorts): 64 + 8
#define XPSTR 72    // kchain halo tile row stride
#define ACSTR 72    // kchain acts row stride
#define CDSTR 88    // kchain cond row stride (80 + 8 pad; ks6 tail reads pad/next row, finite & A=0)
#define M3STR 264   // kfinal mid row stride (shorts): 256 + 8 pad
#define ABSTR 72    // kfinal acts-stage row stride (shorts): 64 + 8 pad

#define A1SZ (NLAYER*8*7*512)   // gate-weight A-frags
#define A2SZ (NLAYER*4*2*512)   // res-weight A-frags
#define SWSZ (16*32*512)        // skip-weight A-frags (M=256, K=1024)
#define OWSZ (16*8*512)         // out/end-weight A-frags (M=256, K=256)
#define AUPSZ (20*10*512)       // upsample A-frags (M=320, K=320)
#define BUPSZ (1000*10*512)     // upsample B-frags (K=320, N=16000)

typedef unsigned short ushort_t;
typedef unsigned long long u64_t;
typedef short v8s __attribute__((ext_vector_type(8)));
typedef short v4s __attribute__((ext_vector_type(4)));
typedef float v4f __attribute__((ext_vector_type(4)));

#define MFMA16 __builtin_amdgcn_mfma_f32_16x16x32_bf16

__device__ __forceinline__ float bf2f(ushort_t u) {
  unsigned int x = ((unsigned int)u) << 16;
  float f; __builtin_memcpy(&f, &x, 4); return f;
}
__device__ __forceinline__ ushort_t f2bf(float f) {
  unsigned int x; __builtin_memcpy(&x, &f, 4);
  x += 0x7fffu + ((x >> 16) & 1u);   // RNE
  return (ushort_t)(x >> 16);
}

// ---------------------------------------------------------------------------
// Prep: pack every weight matrix into exact MFMA fragment order (bf16).
// A-frag: elem j of lane l = A[m = mt*16 + (l&15)][k = ks*32 + (l>>4)*8 + j]
// B-frag: elem j of lane l = B[k = ks*32 + (l>>4)*8 + j][n = nt*16 + (l&15)]
// Also: embed gather -> x0, upsample operands Aup/Bup, barrier zeroing.
// ---------------------------------------------------------------------------
__global__ __launch_bounds__(256) void kprep(
    const float* __restrict__ feat, const int* __restrict__ fin,
    const float* __restrict__ embed, const float* __restrict__ up_w,
    const float* __restrict__ cond_w, const float* __restrict__ cond_b,
    const float* __restrict__ dil_w, const float* __restrict__ dil_b,
    const float* __restrict__ res_w, const float* __restrict__ skip_w,
    const float* __restrict__ skip_b, const float* __restrict__ out_w,
    const float* __restrict__ end_w,
    ushort_t* __restrict__ A1, ushort_t* __restrict__ A2,
    ushort_t* __restrict__ SWf, ushort_t* __restrict__ OWf,
    ushort_t* __restrict__ EWf, ushort_t* __restrict__ Aup,
    ushort_t* __restrict__ Bup, ushort_t* __restrict__ x0,
    float* __restrict__ Bcomb, float* __restrict__ SBsum,
    unsigned int* __restrict__ bar) {
  int tid = blockIdx.x * 256 + threadIdx.x;
  int np = gridDim.x * 256;
  // zero the kchain grid-barrier state (re-zeroed every iteration/replay)
  for (int idx = tid; idx < BARSZ; idx += np) bar[idx] = 0u;
  // A1: gate GEMM [16 layers][8 Mtiles][7 Ksteps][64 lanes][8]
  // K rows: 0..63 = xc (tap1), 64..127 = xp (tap0), 128..207 = cond, pad=0
  for (int idx = tid; idx < A1SZ; idx += np) {
    int j = idx & 7, lane = (idx >> 3) & 63;
    int r_ = idx >> 9;
    int ks = r_ % 7; int r2 = r_ / 7;
    int mt = r2 & 7; int i = r2 >> 3;
    int m = mt * 16 + (lane & 15);
    int k = ks * 32 + (lane >> 4) * 8 + j;
    float v = 0.f;
    if (k < 64)       v = dil_w[((i * 128 + m) * 64 + k) * 2 + 1];
    else if (k < 128) v = dil_w[((i * 128 + m) * 64 + (k - 64)) * 2 + 0];
    else if (k < 208) v = cond_w[(i * 128 + m) * 80 + (k - 128)];
    A1[idx] = f2bf(v);
  }
  // A2: res GEMM [16][4 Mtiles][2 Ksteps][64][8] (layer 15 zeroed/unused)
  for (int idx = tid; idx < A2SZ; idx += np) {
    int j = idx & 7, lane = (idx >> 3) & 63;
    int r_ = idx >> 9;
    int ks = r_ & 1; int mt = (r_ >> 1) & 3; int i = r_ >> 3;
    int m = mt * 16 + (lane & 15);
    int k = ks * 32 + (lane >> 4) * 8 + j;
    A2[idx] = f2bf(i < 15 ? res_w[(i * 64 + m) * 64 + k] : 0.f);
  }
  // SWf: skip GEMM [16 Mtiles][32 Ksteps][64][8], K = layer*64 + ch
  for (int idx = tid; idx < SWSZ; idx += np) {
    int j = idx & 7, lane = (idx >> 3) & 63;
    int r_ = idx >> 9;
    int ks = r_ & 31; int mt = r_ >> 5;
    int m = mt * 16 + (lane & 15);
    int k = ks * 32 + (lane >> 4) * 8 + j;
    int i = k >> 6, ch = k & 63;
    SWf[idx] = f2bf(skip_w[(i * 256 + m) * 64 + ch]);
  }
  // OWf/EWf: [16 Mtiles][8 Ksteps][64][8]
  for (int idx = tid; idx < OWSZ; idx += np) {
    int j = idx & 7, lane = (idx >> 3) & 63;
    int r_ = idx >> 9;
    int ks = r_ & 7; int mt = r_ >> 3;
    int m = mt * 16 + (lane & 15);
    int k = ks * 32 + (lane >> 4) * 8 + j;
    OWf[idx] = f2bf(out_w[m * 256 + k]);
    EWf[idx] = f2bf(end_w[m * 256 + k]);
  }
  // Aup: [20 Mtiles][10 Ks][64][8]; A[mrow=(b*80+q)][km=(m*80+i)] =
  //   feat[b,i,q-m] (0 if q<m)
  for (int idx = tid; idx < AUPSZ; idx += np) {
    int j = idx & 7, lane = (idx >> 3) & 63;
    int r_ = idx >> 9;
    int ks = r_ % 10; int mt = r_ / 10;
    int mrow = mt * 16 + (lane & 15);
    int km = ks * 32 + (lane >> 4) * 8 + j;
    int b = mrow / 80, q = mrow % 80;
    int m = km / 80, i = km % 80;
    int jj = q - m;
    Aup[idx] = f2bf(jj >= 0 ? feat[(b * 80 + i) * 80 + jj] : 0.f);
  }
  // Bup: [1000 Ntiles][10 Ks][64][8]; B[km][col=(o*200+r)] =
  //   up_w[i, o, 200m + r]  (16 consecutive lanes read 16 consecutive floats)
  for (int idx = tid; idx < BUPSZ; idx += np) {
    int j = idx & 7, lane = (idx >> 3) & 63;
    int r_ = idx >> 9;
    int ks = r_ % 10; int nt = r_ / 10;
    int km = ks * 32 + (lane >> 4) * 8 + j;
    int m = km / 80, i = km % 80;
    int col = nt * 16 + (lane & 15);
    int o = col / 200, r = col % 200;
    Bup[idx] = f2bf(up_w[(size_t)(i * 80 + o) * 800 + m * 200 + r]);
  }
  // embed gather: x0[b][t][ch] bf16
  for (int idx = tid; idx < BB * TT * 64; idx += np) {
    int k = idx & 63;
    int bt = idx >> 6;            // b*TT + t
    x0[idx] = f2bf(embed[fin[bt] * 64 + k]);
  }
  for (int idx = tid; idx < NLAYER * 128; idx += np)
    Bcomb[idx] = dil_b[idx] + cond_b[idx];
  for (int idx = tid; idx < 256; idx += np) {
    float s = 0.f;
    for (int i = 0; i < NLAYER; i++) s += skip_b[i * 256 + idx];
    SBsum[idx] = s;
  }
}

// ---------------------------------------------------------------------------
// Upsample GEMM, MFMA: M=320 (b,q), K=320 (m,i), N=16000 (o*200+r).
// Output cond TRANSPOSED: condT[b][o][t], t = q*200+r (r9-proven: coalesced
// 32B runs vs the old [t][80] layout's 2B-at-160B-stride scatter).
// ---------------------------------------------------------------------------
__global__ __launch_bounds__(256) void kup(
    const ushort_t* __restrict__ Aup, const ushort_t* __restrict__ Bup,
    const float* __restrict__ up_b, ushort_t* __restrict__ condT) {
  int nt0 = blockIdx.x * 4;
  int lane = threadIdx.x & 63;
  int w = threadIdx.x >> 6;
  int tl = lane & 15, quad = lane >> 4;
  v4f acc[5][4];
  #pragma unroll
  for (int mt = 0; mt < 5; mt++)
    #pragma unroll
    for (int nt = 0; nt < 4; nt++) acc[mt][nt] = 0.f;
  #pragma unroll
  for (int ks = 0; ks < 10; ks++) {
    v8s bf[4];
    #pragma unroll
    for (int nt = 0; nt < 4; nt++)
      bf[nt] = *(const v8s*)(Bup + (((size_t)(nt0 + nt) * 10 + ks) * 64 + lane) * 8);
    #pragma unroll
    for (int mt = 0; mt < 5; mt++) {
      v8s a = *(const v8s*)(Aup + (((size_t)(w * 5 + mt) * 10 + ks) * 64 + lane) * 8);
      #pragma unroll
      for (int nt = 0; nt < 4; nt++)
        acc[mt][nt] = MFMA16(a, bf[nt], acc[mt][nt], 0, 0, 0);
    }
  }
  #pragma unroll
  for (int mt = 0; mt < 5; mt++) {
    #pragma unroll
    for (int nt = 0; nt < 4; nt++) {
      int col = (nt0 + nt) * 16 + tl;
      int o = col / 200, r = col % 200;
      float bias = up_b[o];
      #pragma unroll
      for (int rg = 0; rg < 4; rg++) {
        int mrow = (w * 5 + mt) * 16 + quad * 4 + rg;
        int b = mrow / 80, q = mrow % 80;
        condT[((size_t)b * 80 + o) * TT + q * 200 + r] =
            f2bf(acc[mt][nt][rg] + bias);
      }
    }
  }
}

// ---------------------------------------------------------------------------
// Fused 16-layer WaveNet chain — r10 structure (196 us measured), one change:
// the gate nonlinearity's two IEEE divides (each ~10-instr div_scale/
// div_fmas/div_fixup sequences without fast-math) are replaced with
// v_rcp_f32 (+1 mul). ~320 VALU instr/thread/layer -> ~64; denominators
// are in (1,2] so rcp's ~1ulp error vanishes in bf16 rounding.
// Sync: hierarchical barrier + relaxed agent atomics only (r3/r4 lessons).
// ---------------------------------------------------------------------------
__global__ __launch_bounds__(256, 4) void kchain(
    ushort_t* __restrict__ x0g, ushort_t* __restrict__ x1g,
    const ushort_t* __restrict__ condT, ushort_t* __restrict__ actsb,
    const ushort_t* __restrict__ A1, const ushort_t* __restrict__ A2,
    const float* __restrict__ Bcomb, const float* __restrict__ resb,
    unsigned int* __restrict__ bar) {
  __shared__ ushort_t Uxc[64 * XCSTR];       // 9.0 KB current x tile
  __shared__ ushort_t Uhalo[64 * XPSTR];     // 9.0 KB halo rows (t < d)
  __shared__ ushort_t Uact[64 * ACSTR];      // 9.0 KB gate acts
  __shared__ ushort_t Ucd[64 * CDSTR + 8];   // 11.0 KB cond tile (+tail pad)
  int b = blockIdx.y;
  int t0 = blockIdx.x * 64;
  int tidx = threadIdx.x;
  int lane = tidx & 63;
  int w = tidx >> 6;
  int tl = lane & 15, quad = lane >> 4;
  int cha = w * 16 + quad * 4;
  const size_t lstr = (size_t)BB * TT * 64;

  // ---- one-time stage: Uxc <- x0, Ucd <- condT (transposing), pad ----
  const ushort_t* xb0 = x0g + ((size_t)b * TT + t0) * 64;
  for (int e = tidx * 8; e < 4096; e += 2048) {
    int t = e >> 6, c = e & 63;
    *(v8s*)&Uxc[t * XCSTR + c] = *(const v8s*)(xb0 + e);
  }
  for (int e = tidx; e < 5120; e += 256) {
    int c = e >> 6, t = e & 63;   // consecutive tidx -> consecutive t: 128B rows
    Ucd[t * CDSTR + c] = condT[((size_t)b * 80 + c) * TT + t0 + t];
  }
  // zero pad cols 80..87 every row + 8 tail shorts (ks6 reads must be finite)
  for (int e2 = tidx; e2 < 520; e2 += 256) {
    if (e2 < 512) Ucd[(e2 >> 3) * CDSTR + 80 + (e2 & 7)] = 0;
    else          Ucd[64 * CDSTR + (e2 - 512)] = 0;
  }
  __syncthreads();

  for (int l = 0; l < NLAYER; l++) {
    int d = 1 << (l & 7);
    int hr = (d < 64) ? d : 64;                 // halo rows staged this layer
    const ushort_t* xing = (l & 1) ? x1g : x0g;
    ushort_t* xoutg = (l & 1) ? x0g : x1g;
    const ushort_t* A1l = A1 + (size_t)l * 8 * 7 * 512;
    const ushort_t* A2l = A2 + (size_t)l * 4 * 2 * 512;
    const float* Bb = Bcomb + l * 128;
    const float* rb = resb + (l < 15 ? l : 0) * 64;
    int last = (l == NLAYER - 1);

    // ---- stage Uhalo: ONLY rows t<hr, from left neighbor (LLC atomics) ----
    for (int e = tidx * 8; e < hr * 64; e += 2048) {
      int t = e >> 6, c = e & 63;
      int tp = t0 + t - d;
      v8s v = (v8s)0;
      if (tp >= 0) {
        const u64_t* p = (const u64_t*)(xing + ((size_t)b * TT + tp) * 64 + c);
        u64_t w0 = __hip_atomic_load(p, __ATOMIC_RELAXED, __HIP_MEMORY_SCOPE_AGENT);
        u64_t w1 = __hip_atomic_load(p + 1, __ATOMIC_RELAXED, __HIP_MEMORY_SCOPE_AGENT);
        __builtin_memcpy(&v, &w0, 8);
        __builtin_memcpy(((char*)&v) + 8, &w1, 8);
      }
      *(v8s*)&Uhalo[t * XPSTR + c] = v;
    }
    __syncthreads();

    // ---- stage 1: gate GEMM (xc from Uxc rows t; xp from Uxc[t-d] or
    //      Uhalo[t]; cond from Ucd) ----
    v4f acc0[4], acc1[4];
    #pragma unroll
    for (int nt = 0; nt < 4; nt++) { acc0[nt] = 0.f; acc1[nt] = 0.f; }
    #pragma unroll
    for (int ks = 0; ks < 7; ks++) {
      v8s a0 = *(const v8s*)(A1l + (((size_t)w * 7 + ks) * 64 + lane) * 8);
      v8s a1 = *(const v8s*)(A1l + (((size_t)(w + 4) * 7 + ks) * 64 + lane) * 8);
      #pragma unroll
      for (int nt = 0; nt < 4; nt++) {
        int t = nt * 16 + tl;
        const ushort_t* bp;
        if (ks < 2) {
          bp = &Uxc[t * XCSTR + ks * 32 + quad * 8];
        } else if (ks < 4) {
          int toff = t - d;
          bp = (toff >= 0) ? &Uxc[toff * XCSTR + (ks - 2) * 32 + quad * 8]
                           : &Uhalo[t * XPSTR + (ks - 2) * 32 + quad * 8];
        } else {
          bp = &Ucd[t * CDSTR + (ks - 4) * 32 + quad * 8];
        }
        v8s bf = *(const v8s*)bp;
        acc0[nt] = MFMA16(a0, bf, acc0[nt], 0, 0, 0);
        acc1[nt] = MFMA16(a1, bf, acc1[nt], 0, 0, 0);
      }
    }

    // ---- gates: ch = w*16 + quad*4 + r (pair ch, ch+64 lane-local) ----
    float ba[4], bb_[4];
    #pragma unroll
    for (int r = 0; r < 4; r++) { ba[r] = Bb[cha + r]; bb_[r] = Bb[64 + cha + r]; }
    #pragma unroll
    for (int nt = 0; nt < 4; nt++) {
      int t = nt * 16 + tl;
      v4s pk;
      #pragma unroll
      for (int r = 0; r < 4; r++) {
        float ia = acc0[nt][r] + ba[r];
        float ib = acc1[nt][r] + bb_[r];
        float ax = fabsf(ia);
        float e2 = __expf(-2.f * ax);
        float th = __builtin_copysignf(
            (1.f - e2) * __builtin_amdgcn_rcpf(1.f + e2), ia);
        float sg = __builtin_amdgcn_rcpf(1.f + __expf(-ib));
        pk[r] = (short)f2bf(th * sg);
      }
      *(v4s*)&Uact[t * ACSTR + cha] = pk;
    }
    __syncthreads();

    // ---- acts -> global (kfinal's deferred skip GEMM reads these) ----
    ushort_t* ab = actsb + (size_t)l * lstr + ((size_t)b * TT + t0) * 64;
    for (int e = tidx * 8; e < 4096; e += 2048) {
      int t = e >> 6, c = e & 63;
      *(v8s*)(ab + e) = *(const v8s*)&Uact[t * ACSTR + c];
    }

    if (!last) {
      // ---- stage 2: res GEMM + residual, Uxc updated IN PLACE ----
      v4f acc2[4];
      #pragma unroll
      for (int nt = 0; nt < 4; nt++) {
        v4f z;
        #pragma unroll
        for (int r = 0; r < 4; r++) z[r] = rb[cha + r];
        acc2[nt] = z;
      }
      #pragma unroll
      for (int ks = 0; ks < 2; ks++) {
        v8s a = *(const v8s*)(A2l + (((size_t)w * 2 + ks) * 64 + lane) * 8);
        #pragma unroll
        for (int nt = 0; nt < 4; nt++) {
          v8s bf = *(const v8s*)&Uact[(nt * 16 + tl) * ACSTR + ks * 32 + quad * 8];
          acc2[nt] = MFMA16(a, bf, acc2[nt], 0, 0, 0);
        }
      }
      #pragma unroll
      for (int nt = 0; nt < 4; nt++) {
        int t = nt * 16 + tl;
        v4s xo = *(const v4s*)&Uxc[t * XCSTR + cha];
        v4s nw;
        #pragma unroll
        for (int r = 0; r < 4; r++)
          nw[r] = (short)f2bf(acc2[nt][r] + bf2f((ushort_t)xo[r]));
        *(v4s*)&Uxc[t * XCSTR + cha] = nw;
      }
      __syncthreads();   // all channels updated before halo snapshot

      // ---- xout halo rows -> LLC via relaxed agent atomics ----
      int dnext = 1 << ((l + 1) & 7);
      int tmin = 64 - (dnext < 64 ? dnext : 64);
      ushort_t* xob = xoutg + ((size_t)b * TT + t0) * 64;
      for (int e = tidx * 8; e < 4096; e += 2048) {
        int t = e >> 6, c = e & 63;
        if (t >= tmin) {
          v8s v = *(const v8s*)&Uxc[t * XCSTR + c];
          u64_t w0, w1;
          __builtin_memcpy(&w0, &v, 8);
          __builtin_memcpy(&w1, ((const char*)&v) + 8, 8);
          u64_t* p = (u64_t*)(xob + e);
          __hip_atomic_store(p, w0, __ATOMIC_RELAXED, __HIP_MEMORY_SCOPE_AGENT);
          __hip_atomic_store(p + 1, w1, __ATOMIC_RELAXED, __HIP_MEMORY_SCOPE_AGENT);
        }
      }

      // ---- hierarchical grid barrier (shard arrive -> root -> release
      //      broadcast; pollers touch ONLY their shard's release line) ----
      __syncthreads();     // drains vmcnt: halo stores globally visible
      if (tidx == 0) {
        unsigned int* L = bar + l * BARSTR;
        int flat = b * 250 + blockIdx.x;           // 0..999
        int shard = flat & 15;                     // 0..7: 63 blks, 8..15: 62
        unsigned int tgt = (shard < 8) ? 62u : 61u;
        unsigned int old = __hip_atomic_fetch_add(L + shard * 32, 1u,
            __ATOMIC_RELAXED, __HIP_MEMORY_SCOPE_AGENT);
        if (old == tgt) {
          unsigned int ro = __hip_atomic_fetch_add(L + 16 * 32, 1u,
              __ATOMIC_RELAXED, __HIP_MEMORY_SCOPE_AGENT);
          if (ro == 15u) {
            #pragma unroll
            for (int s = 0; s < 16; s++)
              __hip_atomic_store(L + (17 + s) * 32, 1u,
                  __ATOMIC_RELAXED, __HIP_MEMORY_SCOPE_AGENT);
          }
        }
        while (__hip_atomic_load(L + (17 + shard) * 32,
            __ATOMIC_RELAXED, __HIP_MEMORY_SCOPE_AGENT) == 0u)
          __builtin_amdgcn_s_sleep(16);
      }
      __syncthreads();
    }
  }
}

// ---------------------------------------------------------------------------
// Final fused MFMA chain — DEPTH-2 register prefetch pipeline (r8, measured
// ~76us): two named reg sets hold tiles l+1/l+2; the tile ds_written at
// layer l was loaded at l-2, so its vmcnt wait is satisfied and a second
// tile stays in flight across the barrier. Plain loads (acts is
// LLC-resident; NT hints regressed in r9).
// Then +SBsum -> relu -> out (K=256) -> relu -> end -> shift -> f32 store.
// ---------------------------------------------------------------------------
#define KF_COMPUTE(L, BUF)                                                    \
  {                                                                           \
    _Pragma("unroll")                                                         \
    for (int ks2 = 0; ks2 < 2; ks2++) {                                       \
      int ksg = (L) * 2 + ks2;                                                \
      v8s bf[4];                                                              \
      _Pragma("unroll")                                                       \
      for (int nt = 0; nt < 4; nt++)                                          \
        bf[nt] = *(const v8s*)&(BUF)[(nt * 16 + tl) * ABSTR + ks2 * 32 +      \
                                     quad * 8];                               \
      _Pragma("unroll")                                                       \
      for (int mt = 0; mt < 4; mt++) {                                        \
        v8s a = *(const v8s*)(SWf +                                           \
            (((size_t)(w * 4 + mt) * 32 + ksg) * 64 + lane) * 8);             \
        _Pragma("unroll")                                                     \
        for (int nt = 0; nt < 4; nt++)                                        \
          acc[mt][nt] = MFMA16(a, bf[nt], acc[mt][nt], 0, 0, 0);              \
      }                                                                       \
    }                                                                         \
  }

__global__ __launch_bounds__(256) void kfinal(
    const ushort_t* __restrict__ actsb,
    const ushort_t* __restrict__ SWf, const ushort_t* __restrict__ OWf,
    const ushort_t* __restrict__ EWf, const float* __restrict__ SBsum,
    float* __restrict__ dout) {
  __shared__ ushort_t SMEM[64 * M3STR];   // 33 KB; skip-phase: AB dbuf, then M3
  int b = blockIdx.y;
  int t0 = blockIdx.x * 64;
  int tidx = threadIdx.x;
  int lane = tidx & 63;
  int w = tidx >> 6;
  int tl = lane & 15, quad = lane >> 4;

  // ---- skip GEMM, K = 16 layers * 64 ch ----
  v4f acc[4][4];
  #pragma unroll
  for (int mt = 0; mt < 4; mt++) {
    int o = (w * 4 + mt) * 16 + quad * 4;
    #pragma unroll
    for (int nt = 0; nt < 4; nt++) {
      v4f z;
      #pragma unroll
      for (int r = 0; r < 4; r++) z[r] = SBsum[o + r];
      acc[mt][nt] = z;
    }
  }
  const size_t lstr = (size_t)BB * TT * 64;
  int tq = tidx >> 2;               // t-row this thread copies (0..63)
  int pq = (tidx & 3) * 16;         // 16-short chunk within the row
  const ushort_t* a0p = actsb + ((size_t)b * TT + t0) * 64 + tq * 64 + pq;
  {  // stage layer 0 -> buffer 0
    v8s p0 = *(const v8s*)(a0p);
    v8s p1 = *(const v8s*)(a0p + 8);
    *(v8s*)&SMEM[tq * ABSTR + pq] = p0;
    *(v8s*)&SMEM[tq * ABSTR + pq + 8] = p1;
  }
  // issue prefetches: qa = acts(1), qb = acts(2) — both in flight
  v8s qa0 = *(const v8s*)(a0p + 1 * lstr);
  v8s qa1 = *(const v8s*)(a0p + 1 * lstr + 8);
  v8s qb0 = *(const v8s*)(a0p + 2 * lstr);
  v8s qb1 = *(const v8s*)(a0p + 2 * lstr + 8);
  __syncthreads();
  for (int l = 0; l < NLAYER; l += 2) {
    // ---- even layer l: compute from buf0 ----
    KF_COMPUTE(l, SMEM);
    // buf1 <- qa (acts l+1; loaded >=2 layers ago), reissue qa <- acts(l+3)
    *(v8s*)&SMEM[64 * ABSTR + tq * ABSTR + pq] = qa0;
    *(v8s*)&SMEM[64 * ABSTR + tq * ABSTR + pq + 8] = qa1;
    {
      int ln = (l + 3 < NLAYER) ? (l + 3) : (NLAYER - 1);
      qa0 = *(const v8s*)(a0p + (size_t)ln * lstr);
      qa1 = *(const v8s*)(a0p + (size_t)ln * lstr + 8);
    }
    __syncthreads();
    // ---- odd layer l+1: compute from buf1 ----
    KF_COMPUTE(l + 1, SMEM + 64 * ABSTR);
    // buf0 <- qb (acts l+2; dead at l=14), reissue qb <- acts(l+4)
    *(v8s*)&SMEM[tq * ABSTR + pq] = qb0;
    *(v8s*)&SMEM[tq * ABSTR + pq + 8] = qb1;
    {
      int ln = (l + 4 < NLAYER) ? (l + 4) : (NLAYER - 1);
      qb0 = *(const v8s*)(a0p + (size_t)ln * lstr);
      qb1 = *(const v8s*)(a0p + (size_t)ln * lstr + 8);
    }
    __syncthreads();
  }
  // ---- SMEM now reused as M3 [t][256+8] ----
  #pragma unroll
  for (int mt = 0; mt < 4; mt++) {
    int o = (w * 4 + mt) * 16 + quad * 4;
    #pragma unroll
    for (int nt = 0; nt < 4; nt++) {
      int t = nt * 16 + tl;
      #pragma unroll
      for (int r = 0; r < 4; r++)
        SMEM[t * M3STR + o + r] = f2bf(fmaxf(acc[mt][nt][r], 0.f));
    }
  }
  __syncthreads();

  // ---- out GEMM, K=256 ----
  v4f acc2[4][4];
  #pragma unroll
  for (int mt = 0; mt < 4; mt++)
    #pragma unroll
    for (int nt = 0; nt < 4; nt++) acc2[mt][nt] = 0.f;
  #pragma unroll
  for (int ks = 0; ks < 8; ks++) {
    v8s bf[4];
    #pragma unroll
    for (int nt = 0; nt < 4; nt++)
      bf[nt] = *(const v8s*)&SMEM[(nt * 16 + tl) * M3STR + ks * 32 + quad * 8];
    #pragma unroll
    for (int mt = 0; mt < 4; mt++) {
      v8s a = *(const v8s*)(OWf + (((size_t)(w * 4 + mt) * 8 + ks) * 64 + lane) * 8);
      #pragma unroll
      for (int nt = 0; nt < 4; nt++)
        acc2[mt][nt] = MFMA16(a, bf[nt], acc2[mt][nt], 0, 0, 0);
    }
  }
  __syncthreads();   // all M3 reads done before overwrite
  #pragma unroll
  for (int mt = 0; mt < 4; mt++) {
    int o = (w * 4 + mt) * 16 + quad * 4;
    #pragma unroll
    for (int nt = 0; nt < 4; nt++) {
      int t = nt * 16 + tl;
      #pragma unroll
      for (int r = 0; r < 4; r++)
        SMEM[t * M3STR + o + r] = f2bf(fmaxf(acc2[mt][nt][r], 0.f));
    }
  }
  __syncthreads();

  // ---- end GEMM, K=256, then shifted store ----
  v4f acc3[4][4];
  #pragma unroll
  for (int mt = 0; mt < 4; mt++)
    #pragma unroll
    for (int nt = 0; nt < 4; nt++) acc3[mt][nt] = 0.f;
  #pragma unroll
  for (int ks = 0; ks < 8; ks++) {
    v8s bf[4];
    #pragma unroll
    for (int nt = 0; nt < 4; nt++)
      bf[nt] = *(const v8s*)&SMEM[(nt * 16 + tl) * M3STR + ks * 32 + quad * 8];
    #pragma unroll
    for (int mt = 0; mt < 4; mt++) {
      v8s a = *(const v8s*)(EWf + (((size_t)(w * 4 + mt) * 8 + ks) * 64 + lane) * 8);
      #pragma unroll
      for (int nt = 0; nt < 4; nt++)
        acc3[mt][nt] = MFMA16(a, bf[nt], acc3[mt][nt], 0, 0, 0);
    }
  }
  #pragma unroll
  for (int mt = 0; mt < 4; mt++) {
    #pragma unroll
    for (int nt = 0; nt < 4; nt++) {
      int tg = t0 + nt * 16 + tl;
      #pragma unroll
      for (int r = 0; r < 4; r++) {
        int o = (w * 4 + mt) * 16 + quad * 4 + r;
        float* ob = dout + ((size_t)b * 256 + o) * TT;
        if (tg == 0) ob[0] = 0.f;
        if (tg + 1 < TT) ob[tg + 1] = acc3[mt][nt][r];
      }
    }
  }
}

// ---------------------------------------------------------------------------
extern "C" void kernel_launch(void* const* d_in, const int* in_sizes, int n_in,
                              void* d_out, int out_size, void* d_ws, size_t ws_size,
                              hipStream_t stream) {
  const float* feat   = (const float*)d_in[0];
  const int*   fin    = (const int*)d_in[1];
  const float* embed  = (const float*)d_in[2];
  const float* up_w   = (const float*)d_in[3];
  const float* up_b   = (const float*)d_in[4];
  const float* cond_w = (const float*)d_in[5];
  const float* cond_b = (const float*)d_in[6];
  const float* dil_w  = (const float*)d_in[7];
  const float* dil_b  = (const float*)d_in[8];
  const float* res_w  = (const float*)d_in[9];
  const float* res_b  = (const float*)d_in[10];
  const float* skip_w = (const float*)d_in[11];
  const float* skip_b = (const float*)d_in[12];
  const float* out_w  = (const float*)d_in[13];
  const float* end_w  = (const float*)d_in[14];

  // Workspace (~175 MB).
  float* ws = (float*)d_ws;
  unsigned int* bar = (unsigned int*)ws;          // barrier state
  size_t off = BARSZ;
  float* Bcomb = ws + off; off += NLAYER * 128;
  float* SBsum = ws + off; off += 256;
  ushort_t* ub = (ushort_t*)(ws + off);
  size_t uo = 0;
  ushort_t* A1    = ub + uo; uo += A1SZ;
  ushort_t* A2    = ub + uo; uo += A2SZ;
  ushort_t* SWf   = ub + uo; uo += SWSZ;
  ushort_t* OWf   = ub + uo; uo += OWSZ;
  ushort_t* EWf   = ub + uo; uo += OWSZ;
  ushort_t* Aup   = ub + uo; uo += AUPSZ;
  ushort_t* Bup   = ub + uo; uo += BUPSZ;
  ushort_t* condT = ub + uo; uo += (size_t)BB * 80 * TT;
  ushort_t* x0    = ub + uo; uo += (size_t)BB * TT * 64;
  ushort_t* x1    = ub + uo; uo += (size_t)BB * TT * 64;
  ushort_t* acts  = ub + uo; uo += (size_t)NLAYER * BB * TT * 64;  // 131 MB

  kprep<<<1024, 256, 0, stream>>>(feat, fin, embed, up_w, cond_w, cond_b,
      dil_w, dil_b, res_w, skip_w, skip_b, out_w, end_w,
      A1, A2, SWf, OWf, EWf, Aup, Bup, x0, Bcomb, SBsum, bar);
  kup<<<250, 256, 0, stream>>>(Aup, Bup, up_b, condT);
  kchain<<<dim3(250, BB), 256, 0, stream>>>(x0, x1, condT, acts,
      A1, A2, Bcomb, res_b, bar);
  kfinal<<<dim3(250, BB), 256, 0, stream>>>(acts, SWf, OWf, EWf, SBsum,
      (float*)d_out);
}